// Round 2
// baseline (6233.230 us; speedup 1.0000x reference)
//
// Seq2Seq BiLSTM (B=256,T=96,D=64,H=256,L=5, dec H2=512, P=14) — round 2.
// Change vs r1: 480 enc_step launches -> 5 persistent enc_layer kernels.
// Pair-of-WGs per (dir,batch16): weights VGPR-resident (frag-major, packed by
// prep), c-state in registers, h ping-pong via global + flag sync (agent-scope
// atomics), K-split-2 partial-sum exchange via LDS. gemm_xg/dec/fc unchanged.
#include <hip/hip_runtime.h>

typedef _Float16 f16;
using half8 = __attribute__((ext_vector_type(8))) _Float16;
using half4 = __attribute__((ext_vector_type(4))) _Float16;
using f32x4 = __attribute__((ext_vector_type(4))) float;

#define DEV __device__ __forceinline__
#define LD8(p) (*(const half8*)(const void*)(p))

DEV f32x4 mfma16(half8 a, half8 b, f32x4 c) {
  return __builtin_amdgcn_mfma_f32_16x16x32_f16(a, b, c, 0, 0, 0);
}
DEV float sigf(float x) { return 1.f / (1.f + __expf(-x)); }
DEV float tanhf2(float x) { float e = __expf(2.f * x); return 1.f - 2.f / (e + 1.f); }

// ---- workspace layout (byte offsets, all 256-aligned; total ~194 MB) ----
static const size_t OFF_WIH0   = 0;          // [2][1024][64] f16
static const size_t OFF_WIH14  = 262144;     // [4][2][1024][512] f16
static const size_t OFF_WHH    = 8650752;    // frag-major [5][d][hf][wid16][f16][512] f16
static const size_t OFF_WDEC0  = 13893632;   // [2048][576] f16 ([Wih|Whh])
static const size_t OFF_WDEC14 = 16252928;   // [4][2048][1024] f16
static const size_t OFF_WFC    = 33030144;   // [64][512] f16
static const size_t OFF_X16    = 33095680;   // [96][256][64] f16
static const size_t OFF_SEQA   = 36241408;   // [96][256][512] f16
static const size_t OFF_SEQB   = 61407232;   // [96][256][512] f16
static const size_t OFF_XG     = 86573056;   // frag-major [2][1536][64][64][4] f16
static const size_t OFF_HBUF   = 187236352;  // [16bb][2d][2hf][2par][16][128] f16 (reused EHDB)
static const size_t OFF_FLAGS  = 187760640;  // 64 ints (reused ECST region)
static const size_t OFF_DHDB   = 188284928;  // [2][5][256][512] f16 (parity,layer)
static const size_t OFF_DCST   = 190906368;  // [5][256][512] f32
static const size_t OFF_ZFC    = 193527808;  // [256][512] f16 (cols 0..63 used)

// ---------------- prep: convert/pack weights + x to f16 -------------------
__global__ __launch_bounds__(256) void prep(
    const float* __restrict__ x,
    const float* __restrict__ eWih0, const float* __restrict__ eWhh0,
    const float* __restrict__ eWih,  const float* __restrict__ eWhh,
    const float* __restrict__ dWih0, const float* __restrict__ dWhh0,
    const float* __restrict__ dWih,  const float* __restrict__ dWhh,
    const float* __restrict__ fcW,   char* __restrict__ ws)
{
  f16* wih0   = (f16*)(ws + OFF_WIH0);
  f16* wih14  = (f16*)(ws + OFF_WIH14);
  f16* whhf   = (f16*)(ws + OFF_WHH);
  f16* wdec0  = (f16*)(ws + OFF_WDEC0);
  f16* wdec14 = (f16*)(ws + OFF_WDEC14);
  f16* wfc    = (f16*)(ws + OFF_WFC);
  f16* x16    = (f16*)(ws + OFF_X16);
  f16* zfc    = (f16*)(ws + OFF_ZFC);
  int* flags  = (int*)(ws + OFF_FLAGS);
  const size_t total = 18137152;
  for (size_t i = (size_t)blockIdx.x * blockDim.x + threadIdx.x; i < total;
       i += (size_t)gridDim.x * blockDim.x) {
    size_t j = i;
    if (j < 131072) { wih0[j] = (f16)eWih0[j]; continue; }
    j -= 131072;
    if (j < 4194304) { wih14[j] = (f16)eWih[j]; continue; }
    j -= 4194304;
    if (j < 2621440) {  // Whh -> frag-major for enc_layer (dest linear = j)
      size_t l = j >> 19, i2 = j & 524287;
      int d   = (int)(i2 >> 18);
      int hfv = (int)((i2 >> 17) & 1);
      int w   = (int)((i2 >> 13) & 15);
      int f   = (int)((i2 >> 9) & 15);
      int lnv = (int)((i2 >> 3) & 63);
      int e   = (int)(i2 & 7);
      int g = f >> 2, kc = f & 3, kh = w >> 3, ug = w & 7;
      int unit = hfv * 128 + ug * 16 + (lnv & 15);
      int k = ((kh == 0 ? hfv : 1 - hfv) * 128) + kc * 32 + (lnv >> 4) * 8 + e;
      int row = g * 256 + unit;
      float v = (l == 0) ? eWhh0[((size_t)d * 1024 + row) * 256 + k]
                         : eWhh[((((l - 1) * 2 + (size_t)d) * 1024) + row) * 256 + k];
      whhf[j] = (f16)v;
      continue;
    }
    j -= 2621440;
    if (j < 1179648) {  // dec layer0: [2048][64|512] -> [2048][576]
      size_t r = j / 576, c = j % 576;
      wdec0[j] = (f16)((c < 64) ? dWih0[r * 64 + c] : dWhh0[r * 512 + (c - 64)]);
      continue;
    }
    j -= 1179648;
    if (j < 8388608) {  // dec layers1-4: [2048][512|512] -> [2048][1024]
      size_t l = j >> 21, rem = j & 2097151;
      size_t r = rem >> 10, c = rem & 1023;
      wdec14[j] = (f16)((c < 512) ? dWih[(l * 2048 + r) * 512 + c]
                                  : dWhh[(l * 2048 + r) * 512 + (c - 512)]);
      continue;
    }
    j -= 8388608;
    if (j < 32768) { wfc[j] = (f16)fcW[j]; continue; }
    j -= 32768;
    if (j < 1572864) {  // x (B,T,D) -> x16 [t][b][d]
      size_t t = j >> 14, rem = j & 16383;
      size_t b = rem >> 6, d = rem & 63;
      x16[j] = (f16)x[(b * 96 + t) * 64 + d];
      continue;
    }
    j -= 1572864;
    if (j < 16384) {  // decoder first input = x[:, -1, :]
      size_t b = j >> 6, d = j & 63;
      zfc[b * 512 + d] = (f16)x[(b * 96 + 95) * 64 + d];
      continue;
    }
    j -= 16384;
    flags[j] = 0;  // 64 sync flags (ws is poisoned 0xAA each call)
  }
}

// ------------- phase A: Xg[dir][t,b][4H] = in @ Wih^T + (bih+bhh) ---------
__global__ __launch_bounds__(256) void gemm_xg(
    const f16* __restrict__ A, int K, const f16* __restrict__ W,
    const float* __restrict__ bih, const float* __restrict__ bhh,
    f16* __restrict__ xg)
{
  __shared__ __align__(16) f16 As[128 * 32];
  __shared__ __align__(16) f16 Ws[128 * 32];
  const int dir = blockIdx.y >> 3;
  const int cb  = (blockIdx.y & 7) * 128;
  const int rb  = blockIdx.x * 128;
  const int tid = threadIdx.x;
  const int wv = tid >> 6, ln = tid & 63;
  const int wr = wv >> 1, wc = wv & 1;
  const f16* Wd = W + (size_t)dir * 1024 * K;

  f32x4 acc[4][4];
#pragma unroll
  for (int m = 0; m < 4; m++)
#pragma unroll
    for (int n = 0; n < 4; n++) acc[m][n] = (f32x4){0.f, 0.f, 0.f, 0.f};

  const int sr = tid >> 1;
  const int sk = (tid & 1) * 16;
  const int nk = K >> 5;
  for (int kt = 0; kt < nk; ++kt) {
    half8 va0 = LD8(&A[(size_t)(rb + sr) * K + kt * 32 + sk]);
    half8 va1 = LD8(&A[(size_t)(rb + sr) * K + kt * 32 + sk + 8]);
    half8 vw0 = LD8(&Wd[(size_t)(cb + sr) * K + kt * 32 + sk]);
    half8 vw1 = LD8(&Wd[(size_t)(cb + sr) * K + kt * 32 + sk + 8]);
    *(half8*)&As[sr * 32 + sk] = va0;
    *(half8*)&As[sr * 32 + sk + 8] = va1;
    *(half8*)&Ws[sr * 32 + sk] = vw0;
    *(half8*)&Ws[sr * 32 + sk + 8] = vw1;
    __syncthreads();
    half8 af[4], bf[4];
#pragma unroll
    for (int m = 0; m < 4; m++)
      af[m] = LD8(&As[(wr * 64 + m * 16 + (ln & 15)) * 32 + (ln >> 4) * 8]);
#pragma unroll
    for (int n = 0; n < 4; n++)
      bf[n] = LD8(&Ws[(wc * 64 + n * 16 + (ln & 15)) * 32 + (ln >> 4) * 8]);
#pragma unroll
    for (int m = 0; m < 4; m++)
#pragma unroll
      for (int n = 0; n < 4; n++) acc[m][n] = mfma16(af[m], bf[n], acc[m][n]);
    __syncthreads();
  }
#pragma unroll
  for (int n = 0; n < 4; n++) {
    const int col = cb + wc * 64 + n * 16 + (ln & 15);
    const float bsum = bih[dir * 1024 + col] + bhh[dir * 1024 + col];
    const int c16 = (cb + wc * 64 + n * 16) >> 4;
#pragma unroll
    for (int m = 0; m < 4; m++) {
      const int r16 = (rb + wr * 64 + m * 16) >> 4;
      half4 h;
#pragma unroll
      for (int r = 0; r < 4; r++) h[r] = (f16)(acc[m][n][r] + bsum);
      *(half4*)&xg[(((size_t)dir * 1536 + r16) * 64 + c16) * 256 + ln * 4] = h;
    }
  }
}

// --------- persistent encoder layer: 96 steps, weights in VGPRs -----------
// grid (16,2,2): x=batch16, y=dir, z=unit-half. block 1024 (16 waves).
// wave wid: ug=wid&7 (16-unit group), kh=wid>>3 (0: local-K half, 1: remote).
// Weights: 16 b-frags/wave (64 VGPR) from frag-major whhf. c-state in regs.
// h ping-pong in global hbuf; pair (z=0,z=1) syncs via monotonic step flags.
__global__ __launch_bounds__(1024) void enc_layer(
    const f16* __restrict__ xg, const f16* __restrict__ whhf,
    f16* __restrict__ hbuf, int* __restrict__ flags,
    f16* __restrict__ seqo, f16* __restrict__ hfin, float* __restrict__ cfin,
    int layer)
{
  const int bb = blockIdx.x, d = blockIdx.y, hf = blockIdx.z;
  const int tid = threadIdx.x;
  const int wid = tid >> 6, ln = tid & 63;
  const int ug = wid & 7, kh = wid >> 3;
  const int lc = ln & 15, lk = ln >> 4;

  __shared__ __align__(16) char exch[32 * 1280];  // 8ug x 4g tiles, col stride 80B

  // one-time weight load (coalesced: prep packed frag-major)
  half8 wfr[16];
  const f16* wbase = whhf + ((((size_t)d * 2 + hf) * 16 + wid) * 16) * 512;
#pragma unroll
  for (int f = 0; f < 16; f++) wfr[f] = LD8(&wbase[f * 512 + ln * 8]);

  f16* hown = hbuf + ((((size_t)bb * 2 + d) * 2 + hf) * 2) * 2048;
  const f16* hpart = hbuf + ((((size_t)bb * 2 + d) * 2 + (hf ^ 1)) * 2) * 2048;
  int* myflag = &flags[(bb * 2 + d) * 2 + hf];
  int* pflag  = &flags[(bb * 2 + d) * 2 + (hf ^ 1)];
  const int base = layer * 96;
  const int rowbase = bb * 16;

  f32x4 cst = (f32x4){0.f, 0.f, 0.f, 0.f};  // cell state (kh0 lanes)

  for (int t = 0; t < 96; ++t) {
    const int tt = d ? 95 - t : t;
    f32x4 acc[4];
    if (kh == 0) {  // init from xg (x@Wih^T + bias), frag-major
      const int r16 = tt * 16 + bb;
#pragma unroll
      for (int g = 0; g < 4; g++) {
        const int c16 = (g * 256 + hf * 128 + ug * 16) >> 4;
        half4 v = *(const half4*)&xg[(((size_t)d * 1536 + r16) * 64 + c16) * 256 + ln * 4];
        acc[g] = (f32x4){(float)v[0], (float)v[1], (float)v[2], (float)v[3]};
      }
    } else {
#pragma unroll
      for (int g = 0; g < 4; g++) acc[g] = (f32x4){0.f, 0.f, 0.f, 0.f};
    }

    if (t > 0) {
      const f16* hsrc;
      if (kh == 0) {
        hsrc = hown + ((t - 1) & 1) * 2048;  // own half: local L2, no wait
      } else {
        if (ln == 0) {  // wait for partner's step t-1 (relaxed spin, 1 acquire)
          while (__hip_atomic_load(pflag, __ATOMIC_RELAXED,
                                   __HIP_MEMORY_SCOPE_AGENT) < base + t) {}
          (void)__hip_atomic_load(pflag, __ATOMIC_ACQUIRE,
                                  __HIP_MEMORY_SCOPE_AGENT);
        }
        asm volatile("" ::: "memory");  // no load hoisting above the poll
        hsrc = hpart + ((t - 1) & 1) * 2048;
      }
      half8 af[4];
#pragma unroll
      for (int kc = 0; kc < 4; kc++)
        af[kc] = LD8(&hsrc[lc * 128 + kc * 32 + lk * 8]);
#pragma unroll
      for (int g = 0; g < 4; g++)
#pragma unroll
        for (int kc = 0; kc < 4; kc++)
          acc[g] = mfma16(af[kc], wfr[g * 4 + kc], acc[g]);
      if (kh == 1) {  // publish remote-K partials
#pragma unroll
        for (int g = 0; g < 4; g++)
          *(f32x4*)&exch[(ug * 4 + g) * 1280 + lc * 80 + lk * 16] = acc[g];
      }
    }
    __syncthreads();  // S1: partials visible; also protects exch reuse
    if (t > 0 && kh == 0) {
#pragma unroll
      for (int g = 0; g < 4; g++) {
        f32x4 p = *(const f32x4*)&exch[(ug * 4 + g) * 1280 + lc * 80 + lk * 16];
        acc[g] += p;
      }
    }
    if (kh == 0) {  // LSTM cell, fully in registers
      const int cu = hf * 128 + ug * 16 + lc;
      const int uh = ug * 16 + lc;
      f16* hdst = hown + (t & 1) * 2048;
      f16 hv[4];
#pragma unroll
      for (int r = 0; r < 4; r++) {
        float gi = sigf(acc[0][r]);
        float gf = sigf(acc[1][r]);
        float gg = tanhf2(acc[2][r]);
        float go = sigf(acc[3][r]);
        float cn = gf * cst[r] + gi * gg;
        cst[r] = cn;
        hv[r] = (f16)(go * tanhf2(cn));
      }
#pragma unroll
      for (int r = 0; r < 4; r++) {
        const int row = lk * 4 + r;
        hdst[row * 128 + uh] = hv[r];
        seqo[(size_t)tt * 131072 + (size_t)(rowbase + row) * 512 + d * 256 + cu] = hv[r];
      }
      if (t == 95) {  // final states -> decoder init
#pragma unroll
        for (int r = 0; r < 4; r++) {
          const int row = lk * 4 + r;
          hfin[(size_t)(rowbase + row) * 512 + d * 256 + cu] = hv[r];
          cfin[(size_t)(rowbase + row) * 512 + d * 256 + cu] = cst[r];
        }
      }
    }
    __syncthreads();  // S2: all h writes done before flag release
    if (tid == 0)
      __hip_atomic_store(myflag, base + t + 1, __ATOMIC_RELEASE,
                         __HIP_MEMORY_SCOPE_AGENT);
  }
}

// --------- decoder: one layer-eval (gates GEMM over [z|h] + cell) ---------
__global__ __launch_bounds__(128) void dec_step(
    const f16* __restrict__ A0, int K0, const f16* __restrict__ A1,
    const f16* __restrict__ W, int Kt,
    const float* __restrict__ bih, const float* __restrict__ bhh,
    float* __restrict__ cst, f16* __restrict__ h1)
{
  const int u0 = blockIdx.y * 32;
  const int rb = blockIdx.x * 16;
  const int wv = threadIdx.x >> 6, ln = threadIdx.x & 63;
  const int cu = u0 + wv * 16 + (ln & 15);
  f32x4 acc[4];
#pragma unroll
  for (int g = 0; g < 4; g++) {
    float b = bih[g * 512 + cu] + bhh[g * 512 + cu];
    acc[g] = (f32x4){b, b, b, b};
  }
  const int K0c = K0 >> 5, Ktc = Kt >> 5;
  for (int kc = 0; kc < Ktc; kc++) {
    const f16* Ap; int ko;
    if (kc < K0c) { Ap = A0; ko = kc * 32; }
    else          { Ap = A1; ko = (kc - K0c) * 32; }
    half8 a = LD8(&Ap[(size_t)(rb + (ln & 15)) * 512 + ko + (ln >> 4) * 8]);
#pragma unroll
    for (int g = 0; g < 4; g++) {
      half8 b = LD8(&W[(size_t)(g * 512 + cu) * Kt + kc * 32 + (ln >> 4) * 8]);
      acc[g] = mfma16(a, b, acc[g]);
    }
  }
#pragma unroll
  for (int r = 0; r < 4; r++) {
    const int row = rb + (ln >> 4) * 4 + r;
    float gi = sigf(acc[0][r]);
    float gf = sigf(acc[1][r]);
    float gg = tanhf2(acc[2][r]);
    float go = sigf(acc[3][r]);
    float cp = cst[(size_t)row * 512 + cu];
    float cn = gf * cp + gi * gg;
    cst[(size_t)row * 512 + cu] = cn;
    h1[(size_t)row * 512 + cu] = (f16)(go * tanhf2(cn));
  }
}

// --------- FC: out = h4 @ fcW^T + b; writes d_out slice + feedback --------
__global__ __launch_bounds__(64) void fc_kernel(
    const f16* __restrict__ hin, const f16* __restrict__ Wf,
    const float* __restrict__ bf, float* __restrict__ out,
    f16* __restrict__ zfc, int s)
{
  const int rb = blockIdx.x * 16;
  const int ln = threadIdx.x;
  f32x4 acc[4];
#pragma unroll
  for (int n = 0; n < 4; n++) acc[n] = (f32x4){0.f, 0.f, 0.f, 0.f};
#pragma unroll
  for (int kc = 0; kc < 16; kc++) {
    half8 a = LD8(&hin[(size_t)(rb + (ln & 15)) * 512 + kc * 32 + (ln >> 4) * 8]);
#pragma unroll
    for (int n = 0; n < 4; n++) {
      half8 b = LD8(&Wf[(size_t)(n * 16 + (ln & 15)) * 512 + kc * 32 + (ln >> 4) * 8]);
      acc[n] = mfma16(a, b, acc[n]);
    }
  }
#pragma unroll
  for (int n = 0; n < 4; n++) {
    const int col = n * 16 + (ln & 15);
    const float bb = bf[col];
#pragma unroll
    for (int r = 0; r < 4; r++) {
      const int row = rb + (ln >> 4) * 4 + r;
      float v = acc[n][r] + bb;
      out[(size_t)row * 896 + s * 64 + col] = v;
      zfc[(size_t)row * 512 + col] = (f16)v;
    }
  }
}

extern "C" void kernel_launch(void* const* d_in, const int* in_sizes, int n_in,
                              void* d_out, int out_size, void* d_ws, size_t ws_size,
                              hipStream_t stream) {
  char* ws = (char*)d_ws;
  const float* x     = (const float*)d_in[0];
  const float* eWih0 = (const float*)d_in[1];
  const float* eWhh0 = (const float*)d_in[2];
  const float* ebih0 = (const float*)d_in[3];
  const float* ebhh0 = (const float*)d_in[4];
  const float* eWih  = (const float*)d_in[5];
  const float* eWhh  = (const float*)d_in[6];
  const float* ebih  = (const float*)d_in[7];
  const float* ebhh  = (const float*)d_in[8];
  const float* dWih0 = (const float*)d_in[9];
  const float* dWhh0 = (const float*)d_in[10];
  const float* dbih0 = (const float*)d_in[11];
  const float* dbhh0 = (const float*)d_in[12];
  const float* dWih  = (const float*)d_in[13];
  const float* dWhh  = (const float*)d_in[14];
  const float* dbih  = (const float*)d_in[15];
  const float* dbhh  = (const float*)d_in[16];
  const float* fcW   = (const float*)d_in[17];
  const float* fcb   = (const float*)d_in[18];

  f16* xg    = (f16*)(ws + OFF_XG);
  f16* hbuf  = (f16*)(ws + OFF_HBUF);
  int* flags = (int*)(ws + OFF_FLAGS);
  f16* dhdb  = (f16*)(ws + OFF_DHDB);
  float* dcst = (float*)(ws + OFF_DCST);
  f16* zfc   = (f16*)(ws + OFF_ZFC);
  f16* seqA  = (f16*)(ws + OFF_SEQA);
  f16* seqB  = (f16*)(ws + OFF_SEQB);

  prep<<<dim3(2048), dim3(256), 0, stream>>>(x, eWih0, eWhh0, eWih, eWhh,
                                             dWih0, dWhh0, dWih, dWhh, fcW, ws);

  // ---------------- encoder ----------------
  for (int l = 0; l < 5; ++l) {
    const f16* Ain = (l == 0) ? (f16*)(ws + OFF_X16) : ((l & 1) ? seqA : seqB);
    const int K = (l == 0) ? 64 : 512;
    const f16* Wih = (l == 0) ? (f16*)(ws + OFF_WIH0)
                              : (f16*)(ws + OFF_WIH14) + (size_t)(l - 1) * 2 * 1024 * 512;
    const float* bi = (l == 0) ? ebih0 : ebih + (size_t)(l - 1) * 2048;
    const float* bh = (l == 0) ? ebhh0 : ebhh + (size_t)(l - 1) * 2048;
    gemm_xg<<<dim3(192, 16), dim3(256), 0, stream>>>(Ain, K, Wih, bi, bh, xg);

    const f16* whhf_l = (f16*)(ws + OFF_WHH) + (size_t)l * 524288;
    f16* so = (l & 1) ? seqB : seqA;
    enc_layer<<<dim3(16, 2, 2), dim3(1024), 0, stream>>>(
        xg, whhf_l, hbuf, flags, so,
        dhdb + (size_t)l * 131072, dcst + (size_t)l * 131072, l);
  }

  // ---------------- decoder ----------------
  for (int s = 0; s < 14; ++s) {
    const int p = s & 1;
    for (int l = 0; l < 5; ++l) {
      dec_step<<<dim3(16, 16), dim3(128), 0, stream>>>(
          (l == 0) ? zfc : dhdb + (size_t)(p ^ 1) * 655360 + (size_t)(l - 1) * 131072,
          (l == 0) ? 64 : 512,
          dhdb + (size_t)p * 655360 + (size_t)l * 131072,
          (l == 0) ? (f16*)(ws + OFF_WDEC0)
                   : (f16*)(ws + OFF_WDEC14) + (size_t)(l - 1) * 2048 * 1024,
          (l == 0) ? 576 : 1024,
          (l == 0) ? dbih0 : dbih + (size_t)(l - 1) * 2048,
          (l == 0) ? dbhh0 : dbhh + (size_t)(l - 1) * 2048,
          dcst + (size_t)l * 131072,
          dhdb + (size_t)(p ^ 1) * 655360 + (size_t)l * 131072);
    }
    fc_kernel<<<dim3(16), dim3(64), 0, stream>>>(
        dhdb + (size_t)(p ^ 1) * 655360 + 4 * 131072, (f16*)(ws + OFF_WFC), fcb,
        (float*)d_out, zfc, s);
  }
}

// Round 4
// 4406.910 us; speedup vs baseline: 1.4144x; 1.4144x over previous
//
// Seq2Seq BiLSTM (B=256,T=96,D=64,H=256,L=5, dec H2=512, P=14) — round 4.
// r3 resubmission + hang hardening (r3 died to "container failed twice";
// algorithm re-audited clean, suspect infra). Changes vs r3:
//   1) spin tripwire (32k iters ~8ms): deadlock -> wrong answer, not hang.
//   2) #pragma unroll 2 on the 96-step loop (cap code bloat; parity static).
// Design: enc_layer WG=(bb,dir,unit-half), 512thr/8waves, lb(512,2): Whh
// VGPR-resident (128 VGPR/lane frag-major, static idx). Own-half h via
// swizzled LDS; partner-half h + flags via relaxed agent atomics (sc0sc1,
// L3-coherent, no cache fences). vmcnt drain + barrier before flag release.
#include <hip/hip_runtime.h>

typedef _Float16 f16;
using half8 = __attribute__((ext_vector_type(8))) _Float16;
using half4 = __attribute__((ext_vector_type(4))) _Float16;
using f32x4 = __attribute__((ext_vector_type(4))) float;

#define DEV __device__ __forceinline__
#define LD8(p) (*(const half8*)(const void*)(p))

DEV f32x4 mfma16(half8 a, half8 b, f32x4 c) {
  return __builtin_amdgcn_mfma_f32_16x16x32_f16(a, b, c, 0, 0, 0);
}
DEV float sigf(float x) { return 1.f / (1.f + __expf(-x)); }
DEV float tanhf2(float x) { float e = __expf(2.f * x); return 1.f - 2.f / (e + 1.f); }

// ---- workspace layout (byte offsets, all 256-aligned; total ~194 MB) ----
static const size_t OFF_WIH0   = 0;          // [2][1024][64] f16
static const size_t OFF_WIH14  = 262144;     // [4][2][1024][512] f16
static const size_t OFF_WHH    = 8650752;    // frag-major [5][d][uh][w8][g4][kc8][ln64][e8] f16
static const size_t OFF_WDEC0  = 13893632;   // [2048][576] f16 ([Wih|Whh])
static const size_t OFF_WDEC14 = 16252928;   // [4][2048][1024] f16
static const size_t OFF_WFC    = 33030144;   // [64][512] f16
static const size_t OFF_X16    = 33095680;   // [96][256][64] f16
static const size_t OFF_SEQA   = 36241408;   // [96][256][512] f16
static const size_t OFF_SEQB   = 61407232;   // [96][256][512] f16
static const size_t OFF_XG     = 86573056;   // frag-major [2][1536][64][64][4] f16
static const size_t OFF_HBUF   = 187236352;  // [16bb][2d][2uh][2par][16][128] f16
static const size_t OFF_FLAGS  = 187760640;  // 64 ints
static const size_t OFF_DHDB   = 188284928;  // [2][5][256][512] f16 (parity,layer)
static const size_t OFF_DCST   = 190906368;  // [5][256][512] f32
static const size_t OFF_ZFC    = 193527808;  // [256][512] f16 (cols 0..63 used)

// ---------------- prep: convert/pack weights + x to f16 -------------------
__global__ __launch_bounds__(256) void prep(
    const float* __restrict__ x,
    const float* __restrict__ eWih0, const float* __restrict__ eWhh0,
    const float* __restrict__ eWih,  const float* __restrict__ eWhh,
    const float* __restrict__ dWih0, const float* __restrict__ dWhh0,
    const float* __restrict__ dWih,  const float* __restrict__ dWhh,
    const float* __restrict__ fcW,   char* __restrict__ ws)
{
  f16* wih0   = (f16*)(ws + OFF_WIH0);
  f16* wih14  = (f16*)(ws + OFF_WIH14);
  f16* whhf   = (f16*)(ws + OFF_WHH);
  f16* wdec0  = (f16*)(ws + OFF_WDEC0);
  f16* wdec14 = (f16*)(ws + OFF_WDEC14);
  f16* wfc    = (f16*)(ws + OFF_WFC);
  f16* x16    = (f16*)(ws + OFF_X16);
  f16* zfc    = (f16*)(ws + OFF_ZFC);
  int* flags  = (int*)(ws + OFF_FLAGS);
  const size_t total = 18137152;
  for (size_t i = (size_t)blockIdx.x * blockDim.x + threadIdx.x; i < total;
       i += (size_t)gridDim.x * blockDim.x) {
    size_t j = i;
    if (j < 131072) { wih0[j] = (f16)eWih0[j]; continue; }
    j -= 131072;
    if (j < 4194304) { wih14[j] = (f16)eWih[j]; continue; }
    j -= 4194304;
    if (j < 2621440) {  // Whh -> frag-major for enc_layer (dest linear = j)
      size_t l = j >> 19, i2 = j & 524287;
      int d   = (int)(i2 >> 18);
      int uh  = (int)((i2 >> 17) & 1);
      int w   = (int)((i2 >> 14) & 7);
      int g   = (int)((i2 >> 12) & 3);
      int kc  = (int)((i2 >> 9) & 7);
      int lnv = (int)((i2 >> 3) & 63);
      int e   = (int)(i2 & 7);
      int unit = uh * 128 + w * 16 + (lnv & 15);
      int k = kc * 32 + (lnv >> 4) * 8 + e;
      int row = g * 256 + unit;
      float v = (l == 0) ? eWhh0[((size_t)d * 1024 + row) * 256 + k]
                         : eWhh[((((l - 1) * 2 + (size_t)d) * 1024) + row) * 256 + k];
      whhf[j] = (f16)v;
      continue;
    }
    j -= 2621440;
    if (j < 1179648) {  // dec layer0: [2048][64|512] -> [2048][576]
      size_t r = j / 576, c = j % 576;
      wdec0[j] = (f16)((c < 64) ? dWih0[r * 64 + c] : dWhh0[r * 512 + (c - 64)]);
      continue;
    }
    j -= 1179648;
    if (j < 8388608) {  // dec layers1-4: [2048][512|512] -> [2048][1024]
      size_t l = j >> 21, rem = j & 2097151;
      size_t r = rem >> 10, c = rem & 1023;
      wdec14[j] = (f16)((c < 512) ? dWih[(l * 2048 + r) * 512 + c]
                                  : dWhh[(l * 2048 + r) * 512 + (c - 512)]);
      continue;
    }
    j -= 8388608;
    if (j < 32768) { wfc[j] = (f16)fcW[j]; continue; }
    j -= 32768;
    if (j < 1572864) {  // x (B,T,D) -> x16 [t][b][d]
      size_t t = j >> 14, rem = j & 16383;
      size_t b = rem >> 6, d = rem & 63;
      x16[j] = (f16)x[(b * 96 + t) * 64 + d];
      continue;
    }
    j -= 1572864;
    if (j < 16384) {  // decoder first input = x[:, -1, :]
      size_t b = j >> 6, d = j & 63;
      zfc[b * 512 + d] = (f16)x[(b * 96 + 95) * 64 + d];
      continue;
    }
    j -= 16384;
    flags[j] = 0;  // 64 sync flags (ws is poisoned 0xAA each call)
  }
}

// ------------- phase A: Xg[dir][t,b][4H] = in @ Wih^T + (bih+bhh) ---------
__global__ __launch_bounds__(256) void gemm_xg(
    const f16* __restrict__ A, int K, const f16* __restrict__ W,
    const float* __restrict__ bih, const float* __restrict__ bhh,
    f16* __restrict__ xg)
{
  __shared__ __align__(16) f16 As[128 * 32];
  __shared__ __align__(16) f16 Ws[128 * 32];
  const int dir = blockIdx.y >> 3;
  const int cb  = (blockIdx.y & 7) * 128;
  const int rb  = blockIdx.x * 128;
  const int tid = threadIdx.x;
  const int wv = tid >> 6, ln = tid & 63;
  const int wr = wv >> 1, wc = wv & 1;
  const f16* Wd = W + (size_t)dir * 1024 * K;

  f32x4 acc[4][4];
#pragma unroll
  for (int m = 0; m < 4; m++)
#pragma unroll
    for (int n = 0; n < 4; n++) acc[m][n] = (f32x4){0.f, 0.f, 0.f, 0.f};

  const int sr = tid >> 1;
  const int sk = (tid & 1) * 16;
  const int nk = K >> 5;
  for (int kt = 0; kt < nk; ++kt) {
    half8 va0 = LD8(&A[(size_t)(rb + sr) * K + kt * 32 + sk]);
    half8 va1 = LD8(&A[(size_t)(rb + sr) * K + kt * 32 + sk + 8]);
    half8 vw0 = LD8(&Wd[(size_t)(cb + sr) * K + kt * 32 + sk]);
    half8 vw1 = LD8(&Wd[(size_t)(cb + sr) * K + kt * 32 + sk + 8]);
    *(half8*)&As[sr * 32 + sk] = va0;
    *(half8*)&As[sr * 32 + sk + 8] = va1;
    *(half8*)&Ws[sr * 32 + sk] = vw0;
    *(half8*)&Ws[sr * 32 + sk + 8] = vw1;
    __syncthreads();
    half8 af[4], bf[4];
#pragma unroll
    for (int m = 0; m < 4; m++)
      af[m] = LD8(&As[(wr * 64 + m * 16 + (ln & 15)) * 32 + (ln >> 4) * 8]);
#pragma unroll
    for (int n = 0; n < 4; n++)
      bf[n] = LD8(&Ws[(wc * 64 + n * 16 + (ln & 15)) * 32 + (ln >> 4) * 8]);
#pragma unroll
    for (int m = 0; m < 4; m++)
#pragma unroll
      for (int n = 0; n < 4; n++) acc[m][n] = mfma16(af[m], bf[n], acc[m][n]);
    __syncthreads();
  }
#pragma unroll
  for (int n = 0; n < 4; n++) {
    const int col = cb + wc * 64 + n * 16 + (ln & 15);
    const float bsum = bih[dir * 1024 + col] + bhh[dir * 1024 + col];
    const int c16 = (cb + wc * 64 + n * 16) >> 4;
#pragma unroll
    for (int m = 0; m < 4; m++) {
      const int r16 = (rb + wr * 64 + m * 16) >> 4;
      half4 h;
#pragma unroll
      for (int r = 0; r < 4; r++) h[r] = (f16)(acc[m][n][r] + bsum);
      *(half4*)&xg[(((size_t)dir * 1536 + r16) * 64 + c16) * 256 + ln * 4] = h;
    }
  }
}

// --------- persistent encoder layer v2: sync-light, weights in VGPRs ------
// grid (16,4): x=bb, y=d*2+uh. 512 thr / 8 waves. Wave wv owns 16 units
// (unit cu = uh*128+wv*16+lc), FULL K=256: 32 b-frags = 128 VGPR, statically
// indexed (own-K in wfr[g*8+0..3], partner-K in wfr[g*8+4..7]). Own-half h in
// swizzled LDS; partner-half via relaxed agent atomics (L3), lag-1 flag sync.
__global__ __launch_bounds__(512, 2) void enc_layer(
    const f16* __restrict__ xg, const f16* __restrict__ whhf,
    f16* __restrict__ hbuf, int* __restrict__ flags,
    f16* __restrict__ seqo, f16* __restrict__ hfin, float* __restrict__ cfin,
    int layer)
{
  const int bb = blockIdx.x;
  const int d = blockIdx.y >> 1, uh = blockIdx.y & 1;
  const int tid = threadIdx.x;
  const int wv = tid >> 6, ln = tid & 63;
  const int lc = ln & 15, lk = ln >> 4;

  __shared__ __align__(16) char hl[2][4096];  // [par][16 rows][128u], XOR-swz

  // one-time weight load; own-K half -> slots j=0..3, partner-K -> j=4..7
  half8 wfr[32];
  const f16* wbase = whhf + (((size_t)(d * 2 + uh) * 8 + wv) * 16384);
#pragma unroll
  for (int g = 0; g < 4; g++) {
#pragma unroll
    for (int jj = 0; jj < 4; jj++) {
      wfr[g * 8 + jj]     = LD8(&wbase[(size_t)(g * 8 + uh * 4 + jj) * 512 + ln * 8]);
      wfr[g * 8 + 4 + jj] = LD8(&wbase[(size_t)(g * 8 + (1 - uh) * 4 + jj) * 512 + ln * 8]);
    }
  }

  f16* hown = hbuf + ((size_t)((bb * 2 + d) * 2 + uh)) * 4096;
  const f16* hpart = hbuf + ((size_t)((bb * 2 + d) * 2 + (uh ^ 1))) * 4096;
  int* myflag = &flags[(bb * 2 + d) * 2 + uh];
  int* pflag  = &flags[(bb * 2 + d) * 2 + (uh ^ 1)];
  const int base = layer * 96;
  const int rowbase = bb * 16;
  const int unit_local = wv * 16 + lc;  // 0..127
  const int cu = uh * 128 + unit_local; // 0..255

  f32x4 cst = (f32x4){0.f, 0.f, 0.f, 0.f};

#pragma unroll 2
  for (int t = 0; t < 96; ++t) {
    const int tt = d ? 95 - t : t;
    const int par = (t - 1) & 1, par2 = t & 1;
    f32x4 acc[4];
    const int r16 = tt * 16 + bb;
#pragma unroll
    for (int g = 0; g < 4; g++) {  // x@Wih^T + bias from frag-major xg
      half4 v = *(const half4*)&xg[(((size_t)d * 1536 + r16) * 64 +
                                    (g * 16 + uh * 8 + wv)) * 256 + ln * 4];
      acc[g] = (f32x4){(float)v[0], (float)v[1], (float)v[2], (float)v[3]};
    }
    if (t > 0) {
      // 1) wait for partner step t-1 (tripwire: deadlock -> wrong answer,
      //    never a GPU hang), then issue partner-half loads (L3 latency
      //    overlaps own-half MFMAs below)
      unsigned spin = 0;
      while (__hip_atomic_load(pflag, __ATOMIC_RELAXED,
                               __HIP_MEMORY_SCOPE_AGENT) < base + t) {
        if (++spin > 32768u) break;
      }
      asm volatile("" ::: "memory");
      unsigned long long q[4][2];
#pragma unroll
      for (int j = 0; j < 4; j++) {
        const f16* p = &hpart[par * 2048 + lc * 128 + j * 32 + lk * 8];
        q[j][0] = __hip_atomic_load((const unsigned long long*)p,
                                    __ATOMIC_RELAXED, __HIP_MEMORY_SCOPE_AGENT);
        q[j][1] = __hip_atomic_load((const unsigned long long*)(p + 4),
                                    __ATOMIC_RELAXED, __HIP_MEMORY_SCOPE_AGENT);
      }
      // 2) own-half K from swizzled LDS
      half8 ao[4];
#pragma unroll
      for (int j = 0; j < 4; j++) {
        int ba = (lc * 256 + j * 64 + lk * 16) ^ ((lc & 7) << 4);
        ao[j] = *(const half8*)&hl[par][ba];
      }
#pragma unroll
      for (int g = 0; g < 4; g++)
#pragma unroll
        for (int j = 0; j < 4; j++)
          acc[g] = mfma16(ao[j], wfr[g * 8 + j], acc[g]);
      // 3) partner-half K
#pragma unroll
      for (int j = 0; j < 4; j++) {
        union { unsigned long long uq[2]; half8 h; } u;
        u.uq[0] = q[j][0]; u.uq[1] = q[j][1];
#pragma unroll
        for (int g = 0; g < 4; g++)
          acc[g] = mfma16(u.h, wfr[g * 8 + 4 + j], acc[g]);
      }
    }
    // LSTM cell, fully in registers (lane owns 4 rows x 1 unit)
    f16 hv[4];
#pragma unroll
    for (int r = 0; r < 4; r++) {
      float gi = sigf(acc[0][r]);
      float gf = sigf(acc[1][r]);
      float gg = tanhf2(acc[2][r]);
      float go = sigf(acc[3][r]);
      float cn = gf * cst[r] + gi * gg;
      cst[r] = cn;
      hv[r] = (f16)(go * tanhf2(cn));
    }
    // write own h into swizzled LDS tile
#pragma unroll
    for (int r = 0; r < 4; r++) {
      int row = lk * 4 + r;
      int ba = (row * 256 + unit_local * 2) ^ ((row & 7) << 4);
      *(f16*)&hl[par2][ba] = hv[r];
    }
    __syncthreads();  // B1: tile complete before export reads
    // cooperative export: one u64 per thread (row-major, de-swizzled)
    {
      const int row = tid >> 5, c8 = tid & 31;
      int ba = (row * 256 + c8 * 8) ^ ((row & 7) << 4);
      unsigned long long v = *(const unsigned long long*)&hl[par2][ba];
      __hip_atomic_store((unsigned long long*)&hown[par2 * 2048 + row * 128 + c8 * 4],
                         v, __ATOMIC_RELAXED, __HIP_MEMORY_SCOPE_AGENT);
      *(unsigned long long*)&seqo[(size_t)tt * 131072 +
          (size_t)(rowbase + row) * 512 + d * 256 + uh * 128 + c8 * 4] = v;
      if (t == 95)
        *(unsigned long long*)&hfin[(size_t)(rowbase + row) * 512 +
                                    d * 256 + uh * 128 + c8 * 4] = v;
    }
    if (t == 95) {
#pragma unroll
      for (int r = 0; r < 4; r++)
        cfin[(size_t)(rowbase + lk * 4 + r) * 512 + d * 256 + cu] = cst[r];
    }
    asm volatile("s_waitcnt vmcnt(0)" ::: "memory");  // per-wave store drain
    __syncthreads();  // B2: ALL waves drained before flag release
    if (tid == 0)
      __hip_atomic_store(myflag, base + t + 1, __ATOMIC_RELAXED,
                         __HIP_MEMORY_SCOPE_AGENT);
  }
}

// --------- decoder: one layer-eval (gates GEMM over [z|h] + cell) ---------
__global__ __launch_bounds__(128) void dec_step(
    const f16* __restrict__ A0, int K0, const f16* __restrict__ A1,
    const f16* __restrict__ W, int Kt,
    const float* __restrict__ bih, const float* __restrict__ bhh,
    float* __restrict__ cst, f16* __restrict__ h1)
{
  const int u0 = blockIdx.y * 32;
  const int rb = blockIdx.x * 16;
  const int wv = threadIdx.x >> 6, ln = threadIdx.x & 63;
  const int cu = u0 + wv * 16 + (ln & 15);
  f32x4 acc[4];
#pragma unroll
  for (int g = 0; g < 4; g++) {
    float b = bih[g * 512 + cu] + bhh[g * 512 + cu];
    acc[g] = (f32x4){b, b, b, b};
  }
  const int K0c = K0 >> 5, Ktc = Kt >> 5;
  for (int kc = 0; kc < Ktc; kc++) {
    const f16* Ap; int ko;
    if (kc < K0c) { Ap = A0; ko = kc * 32; }
    else          { Ap = A1; ko = (kc - K0c) * 32; }
    half8 a = LD8(&Ap[(size_t)(rb + (ln & 15)) * 512 + ko + (ln >> 4) * 8]);
#pragma unroll
    for (int g = 0; g < 4; g++) {
      half8 b = LD8(&W[(size_t)(g * 512 + cu) * Kt + kc * 32 + (ln >> 4) * 8]);
      acc[g] = mfma16(a, b, acc[g]);
    }
  }
#pragma unroll
  for (int r = 0; r < 4; r++) {
    const int row = rb + (ln >> 4) * 4 + r;
    float gi = sigf(acc[0][r]);
    float gf = sigf(acc[1][r]);
    float gg = tanhf2(acc[2][r]);
    float go = sigf(acc[3][r]);
    float cp = cst[(size_t)row * 512 + cu];
    float cn = gf * cp + gi * gg;
    cst[(size_t)row * 512 + cu] = cn;
    h1[(size_t)row * 512 + cu] = (f16)(go * tanhf2(cn));
  }
}

// --------- FC: out = h4 @ fcW^T + b; writes d_out slice + feedback --------
__global__ __launch_bounds__(64) void fc_kernel(
    const f16* __restrict__ hin, const f16* __restrict__ Wf,
    const float* __restrict__ bf, float* __restrict__ out,
    f16* __restrict__ zfc, int s)
{
  const int rb = blockIdx.x * 16;
  const int ln = threadIdx.x;
  f32x4 acc[4];
#pragma unroll
  for (int n = 0; n < 4; n++) acc[n] = (f32x4){0.f, 0.f, 0.f, 0.f};
#pragma unroll
  for (int kc = 0; kc < 16; kc++) {
    half8 a = LD8(&hin[(size_t)(rb + (ln & 15)) * 512 + kc * 32 + (ln >> 4) * 8]);
#pragma unroll
    for (int n = 0; n < 4; n++) {
      half8 b = LD8(&Wf[(size_t)(n * 16 + (ln & 15)) * 512 + kc * 32 + (ln >> 4) * 8]);
      acc[n] = mfma16(a, b, acc[n]);
    }
  }
#pragma unroll
  for (int n = 0; n < 4; n++) {
    const int col = n * 16 + (ln & 15);
    const float bb = bf[col];
#pragma unroll
    for (int r = 0; r < 4; r++) {
      const int row = rb + (ln >> 4) * 4 + r;
      float v = acc[n][r] + bb;
      out[(size_t)row * 896 + s * 64 + col] = v;
      zfc[(size_t)row * 512 + col] = (f16)v;
    }
  }
}

extern "C" void kernel_launch(void* const* d_in, const int* in_sizes, int n_in,
                              void* d_out, int out_size, void* d_ws, size_t ws_size,
                              hipStream_t stream) {
  char* ws = (char*)d_ws;
  const float* x     = (const float*)d_in[0];
  const float* eWih0 = (const float*)d_in[1];
  const float* eWhh0 = (const float*)d_in[2];
  const float* ebih0 = (const float*)d_in[3];
  const float* ebhh0 = (const float*)d_in[4];
  const float* eWih  = (const float*)d_in[5];
  const float* eWhh  = (const float*)d_in[6];
  const float* ebih  = (const float*)d_in[7];
  const float* ebhh  = (const float*)d_in[8];
  const float* dWih0 = (const float*)d_in[9];
  const float* dWhh0 = (const float*)d_in[10];
  const float* dbih0 = (const float*)d_in[11];
  const float* dbhh0 = (const float*)d_in[12];
  const float* dWih  = (const float*)d_in[13];
  const float* dWhh  = (const float*)d_in[14];
  const float* dbih  = (const float*)d_in[15];
  const float* dbhh  = (const float*)d_in[16];
  const float* fcW   = (const float*)d_in[17];
  const float* fcb   = (const float*)d_in[18];

  f16* xg    = (f16*)(ws + OFF_XG);
  f16* hbuf  = (f16*)(ws + OFF_HBUF);
  int* flags = (int*)(ws + OFF_FLAGS);
  f16* dhdb  = (f16*)(ws + OFF_DHDB);
  float* dcst = (float*)(ws + OFF_DCST);
  f16* zfc   = (f16*)(ws + OFF_ZFC);
  f16* seqA  = (f16*)(ws + OFF_SEQA);
  f16* seqB  = (f16*)(ws + OFF_SEQB);

  prep<<<dim3(2048), dim3(256), 0, stream>>>(x, eWih0, eWhh0, eWih, eWhh,
                                             dWih0, dWhh0, dWih, dWhh, fcW, ws);

  // ---------------- encoder ----------------
  for (int l = 0; l < 5; ++l) {
    const f16* Ain = (l == 0) ? (f16*)(ws + OFF_X16) : ((l & 1) ? seqA : seqB);
    const int K = (l == 0) ? 64 : 512;
    const f16* Wih = (l == 0) ? (f16*)(ws + OFF_WIH0)
                              : (f16*)(ws + OFF_WIH14) + (size_t)(l - 1) * 2 * 1024 * 512;
    const float* bi = (l == 0) ? ebih0 : ebih + (size_t)(l - 1) * 2048;
    const float* bh = (l == 0) ? ebhh0 : ebhh + (size_t)(l - 1) * 2048;
    gemm_xg<<<dim3(192, 16), dim3(256), 0, stream>>>(Ain, K, Wih, bi, bh, xg);

    const f16* whhf_l = (f16*)(ws + OFF_WHH) + (size_t)l * 524288;
    f16* so = (l & 1) ? seqB : seqA;
    enc_layer<<<dim3(16, 4), dim3(512), 0, stream>>>(
        xg, whhf_l, hbuf, flags, so,
        dhdb + (size_t)l * 131072, dcst + (size_t)l * 131072, l);
  }

  // ---------------- decoder ----------------
  for (int s = 0; s < 14; ++s) {
    const int p = s & 1;
    for (int l = 0; l < 5; ++l) {
      dec_step<<<dim3(16, 16), dim3(128), 0, stream>>>(
          (l == 0) ? zfc : dhdb + (size_t)(p ^ 1) * 655360 + (size_t)(l - 1) * 131072,
          (l == 0) ? 64 : 512,
          dhdb + (size_t)p * 655360 + (size_t)l * 131072,
          (l == 0) ? (f16*)(ws + OFF_WDEC0)
                   : (f16*)(ws + OFF_WDEC14) + (size_t)(l - 1) * 2048 * 1024,
          (l == 0) ? 576 : 1024,
          (l == 0) ? dbih0 : dbih + (size_t)(l - 1) * 2048,
          (l == 0) ? dbhh0 : dbhh + (size_t)(l - 1) * 2048,
          dcst + (size_t)l * 131072,
          dhdb + (size_t)(p ^ 1) * 655360 + (size_t)l * 131072);
    }
    fc_kernel<<<dim3(16), dim3(64), 0, stream>>>(
        dhdb + (size_t)(p ^ 1) * 655360 + 4 * 131072, (f16*)(ws + OFF_WFC), fcb,
        (float*)d_out, zfc, s);
  }
}

// Round 5
// 4278.662 us; speedup vs baseline: 1.4568x; 1.0300x over previous
//
// Seq2Seq BiLSTM (B=256,T=96,D=64,H=256,L=5, dec H2=512, P=14) — round 5.
// vs r4: (1) enc_layer: amdgpu_waves_per_eu(2,2) + keep-alive asm => Whh truly
// VGPR-resident (r4's VGPR=108 < 128 needed proved it was not); software
// pipeline: publish h early (store->vmcnt->bar->flag), seqo off critical path,
// own-half MFMA for t+1 computed right after publish (hides partner L3 lat).
// (2) dec_step: grid (4,16), 4 row-blocks/WG, K-outer/row-inner with hoisted
// weight frags (weight panel read 4x not 16x). gemm_xg/fc/prep unchanged.
#include <hip/hip_runtime.h>

typedef _Float16 f16;
using half8 = __attribute__((ext_vector_type(8))) _Float16;
using half4 = __attribute__((ext_vector_type(4))) _Float16;
using f32x4 = __attribute__((ext_vector_type(4))) float;

#define DEV __device__ __forceinline__
#define LD8(p) (*(const half8*)(const void*)(p))

DEV f32x4 mfma16(half8 a, half8 b, f32x4 c) {
  return __builtin_amdgcn_mfma_f32_16x16x32_f16(a, b, c, 0, 0, 0);
}
DEV float sigf(float x) { return 1.f / (1.f + __expf(-x)); }
DEV float tanhf2(float x) { float e = __expf(2.f * x); return 1.f - 2.f / (e + 1.f); }

// ---- workspace layout (byte offsets, all 256-aligned; total ~194 MB) ----
static const size_t OFF_WIH0   = 0;          // [2][1024][64] f16
static const size_t OFF_WIH14  = 262144;     // [4][2][1024][512] f16
static const size_t OFF_WHH    = 8650752;    // frag-major [5][d][uh][w8][g4][kc8][ln64][e8] f16
static const size_t OFF_WDEC0  = 13893632;   // [2048][576] f16 ([Wih|Whh])
static const size_t OFF_WDEC14 = 16252928;   // [4][2048][1024] f16
static const size_t OFF_WFC    = 33030144;   // [64][512] f16
static const size_t OFF_X16    = 33095680;   // [96][256][64] f16
static const size_t OFF_SEQA   = 36241408;   // [96][256][512] f16
static const size_t OFF_SEQB   = 61407232;   // [96][256][512] f16
static const size_t OFF_XG     = 86573056;   // frag-major [2][1536][64][64][4] f16
static const size_t OFF_HBUF   = 187236352;  // [16bb][2d][2uh][2par][16][128] f16
static const size_t OFF_FLAGS  = 187760640;  // 64 ints
static const size_t OFF_DHDB   = 188284928;  // [2][5][256][512] f16 (parity,layer)
static const size_t OFF_DCST   = 190906368;  // [5][256][512] f32
static const size_t OFF_ZFC    = 193527808;  // [256][512] f16 (cols 0..63 used)

// ---------------- prep: convert/pack weights + x to f16 -------------------
__global__ __launch_bounds__(256) void prep(
    const float* __restrict__ x,
    const float* __restrict__ eWih0, const float* __restrict__ eWhh0,
    const float* __restrict__ eWih,  const float* __restrict__ eWhh,
    const float* __restrict__ dWih0, const float* __restrict__ dWhh0,
    const float* __restrict__ dWih,  const float* __restrict__ dWhh,
    const float* __restrict__ fcW,   char* __restrict__ ws)
{
  f16* wih0   = (f16*)(ws + OFF_WIH0);
  f16* wih14  = (f16*)(ws + OFF_WIH14);
  f16* whhf   = (f16*)(ws + OFF_WHH);
  f16* wdec0  = (f16*)(ws + OFF_WDEC0);
  f16* wdec14 = (f16*)(ws + OFF_WDEC14);
  f16* wfc    = (f16*)(ws + OFF_WFC);
  f16* x16    = (f16*)(ws + OFF_X16);
  f16* zfc    = (f16*)(ws + OFF_ZFC);
  int* flags  = (int*)(ws + OFF_FLAGS);
  const size_t total = 18137152;
  for (size_t i = (size_t)blockIdx.x * blockDim.x + threadIdx.x; i < total;
       i += (size_t)gridDim.x * blockDim.x) {
    size_t j = i;
    if (j < 131072) { wih0[j] = (f16)eWih0[j]; continue; }
    j -= 131072;
    if (j < 4194304) { wih14[j] = (f16)eWih[j]; continue; }
    j -= 4194304;
    if (j < 2621440) {  // Whh -> frag-major for enc_layer (dest linear = j)
      size_t l = j >> 19, i2 = j & 524287;
      int d   = (int)(i2 >> 18);
      int uh  = (int)((i2 >> 17) & 1);
      int w   = (int)((i2 >> 14) & 7);
      int g   = (int)((i2 >> 12) & 3);
      int kc  = (int)((i2 >> 9) & 7);
      int lnv = (int)((i2 >> 3) & 63);
      int e   = (int)(i2 & 7);
      int unit = uh * 128 + w * 16 + (lnv & 15);
      int k = kc * 32 + (lnv >> 4) * 8 + e;
      int row = g * 256 + unit;
      float v = (l == 0) ? eWhh0[((size_t)d * 1024 + row) * 256 + k]
                         : eWhh[((((l - 1) * 2 + (size_t)d) * 1024) + row) * 256 + k];
      whhf[j] = (f16)v;
      continue;
    }
    j -= 2621440;
    if (j < 1179648) {  // dec layer0: [2048][64|512] -> [2048][576]
      size_t r = j / 576, c = j % 576;
      wdec0[j] = (f16)((c < 64) ? dWih0[r * 64 + c] : dWhh0[r * 512 + (c - 64)]);
      continue;
    }
    j -= 1179648;
    if (j < 8388608) {  // dec layers1-4: [2048][512|512] -> [2048][1024]
      size_t l = j >> 21, rem = j & 2097151;
      size_t r = rem >> 10, c = rem & 1023;
      wdec14[j] = (f16)((c < 512) ? dWih[(l * 2048 + r) * 512 + c]
                                  : dWhh[(l * 2048 + r) * 512 + (c - 512)]);
      continue;
    }
    j -= 8388608;
    if (j < 32768) { wfc[j] = (f16)fcW[j]; continue; }
    j -= 32768;
    if (j < 1572864) {  // x (B,T,D) -> x16 [t][b][d]
      size_t t = j >> 14, rem = j & 16383;
      size_t b = rem >> 6, d = rem & 63;
      x16[j] = (f16)x[(b * 96 + t) * 64 + d];
      continue;
    }
    j -= 1572864;
    if (j < 16384) {  // decoder first input = x[:, -1, :]
      size_t b = j >> 6, d = j & 63;
      zfc[b * 512 + d] = (f16)x[(b * 96 + 95) * 64 + d];
      continue;
    }
    j -= 16384;
    flags[j] = 0;  // 64 sync flags (ws is poisoned 0xAA each call)
  }
}

// ------------- phase A: Xg[dir][t,b][4H] = in @ Wih^T + (bih+bhh) ---------
__global__ __launch_bounds__(256) void gemm_xg(
    const f16* __restrict__ A, int K, const f16* __restrict__ W,
    const float* __restrict__ bih, const float* __restrict__ bhh,
    f16* __restrict__ xg)
{
  __shared__ __align__(16) f16 As[128 * 32];
  __shared__ __align__(16) f16 Ws[128 * 32];
  const int dir = blockIdx.y >> 3;
  const int cb  = (blockIdx.y & 7) * 128;
  const int rb  = blockIdx.x * 128;
  const int tid = threadIdx.x;
  const int wv = tid >> 6, ln = tid & 63;
  const int wr = wv >> 1, wc = wv & 1;
  const f16* Wd = W + (size_t)dir * 1024 * K;

  f32x4 acc[4][4];
#pragma unroll
  for (int m = 0; m < 4; m++)
#pragma unroll
    for (int n = 0; n < 4; n++) acc[m][n] = (f32x4){0.f, 0.f, 0.f, 0.f};

  const int sr = tid >> 1;
  const int sk = (tid & 1) * 16;
  const int nk = K >> 5;
  for (int kt = 0; kt < nk; ++kt) {
    half8 va0 = LD8(&A[(size_t)(rb + sr) * K + kt * 32 + sk]);
    half8 va1 = LD8(&A[(size_t)(rb + sr) * K + kt * 32 + sk + 8]);
    half8 vw0 = LD8(&Wd[(size_t)(cb + sr) * K + kt * 32 + sk]);
    half8 vw1 = LD8(&Wd[(size_t)(cb + sr) * K + kt * 32 + sk + 8]);
    *(half8*)&As[sr * 32 + sk] = va0;
    *(half8*)&As[sr * 32 + sk + 8] = va1;
    *(half8*)&Ws[sr * 32 + sk] = vw0;
    *(half8*)&Ws[sr * 32 + sk + 8] = vw1;
    __syncthreads();
    half8 af[4], bf[4];
#pragma unroll
    for (int m = 0; m < 4; m++)
      af[m] = LD8(&As[(wr * 64 + m * 16 + (ln & 15)) * 32 + (ln >> 4) * 8]);
#pragma unroll
    for (int n = 0; n < 4; n++)
      bf[n] = LD8(&Ws[(wc * 64 + n * 16 + (ln & 15)) * 32 + (ln >> 4) * 8]);
#pragma unroll
    for (int m = 0; m < 4; m++)
#pragma unroll
      for (int n = 0; n < 4; n++) acc[m][n] = mfma16(af[m], bf[n], acc[m][n]);
    __syncthreads();
  }
#pragma unroll
  for (int n = 0; n < 4; n++) {
    const int col = cb + wc * 64 + n * 16 + (ln & 15);
    const float bsum = bih[dir * 1024 + col] + bhh[dir * 1024 + col];
    const int c16 = (cb + wc * 64 + n * 16) >> 4;
#pragma unroll
    for (int m = 0; m < 4; m++) {
      const int r16 = (rb + wr * 64 + m * 16) >> 4;
      half4 h;
#pragma unroll
      for (int r = 0; r < 4; r++) h[r] = (f16)(acc[m][n][r] + bsum);
      *(half4*)&xg[(((size_t)dir * 1536 + r16) * 64 + c16) * 256 + ln * 4] = h;
    }
  }
}

// --------- persistent encoder layer v3: pipelined, weights in VGPRs -------
// grid (16,4): x=bb, y=d*2+uh. 512 thr / 8 waves, waves_per_eu(2,2) =>
// 256-VGPR budget so the 128-VGPR weight set stays resident (r4: VGPR=108
// proved it was rematerialized). Per step: [poll partner, partner MFMA] ->
// cell -> LDS write -> B1 -> export+publish(hown,vmcnt,B2,flag) -> seqo ->
// own-half MFMA for t+1 (hides partner's flag-propagate + L3 h-load).
__global__ __launch_bounds__(512) __attribute__((amdgpu_waves_per_eu(2, 2)))
void enc_layer(
    const f16* __restrict__ xg, const f16* __restrict__ whhf,
    f16* __restrict__ hbuf, int* __restrict__ flags,
    f16* __restrict__ seqo, f16* __restrict__ hfin, float* __restrict__ cfin,
    int layer)
{
  const int bb = blockIdx.x;
  const int d = blockIdx.y >> 1, uh = blockIdx.y & 1;
  const int tid = threadIdx.x;
  const int wv = tid >> 6, ln = tid & 63;
  const int lc = ln & 15, lk = ln >> 4;

  __shared__ __align__(16) char hl[2][4096];  // [par][16 rows][128u], XOR-swz

  // one-time weight load; own-K half -> slots j=0..3, partner-K -> j=4..7
  half8 wfr[32];
  const f16* wbase = whhf + (((size_t)(d * 2 + uh) * 8 + wv) * 16384);
#pragma unroll
  for (int g = 0; g < 4; g++) {
#pragma unroll
    for (int jj = 0; jj < 4; jj++) {
      wfr[g * 8 + jj]     = LD8(&wbase[(size_t)(g * 8 + uh * 4 + jj) * 512 + ln * 8]);
      wfr[g * 8 + 4 + jj] = LD8(&wbase[(size_t)(g * 8 + (1 - uh) * 4 + jj) * 512 + ln * 8]);
    }
  }
#pragma unroll
  for (int i = 0; i < 32; i++) asm volatile("" : "+v"(wfr[i]));  // pin live

  f16* hown = hbuf + ((size_t)((bb * 2 + d) * 2 + uh)) * 4096;
  const f16* hpart = hbuf + ((size_t)((bb * 2 + d) * 2 + (uh ^ 1))) * 4096;
  int* myflag = &flags[(bb * 2 + d) * 2 + uh];
  int* pflag  = &flags[(bb * 2 + d) * 2 + (uh ^ 1)];
  const int base = layer * 96;
  const int rowbase = bb * 16;
  const int unit_local = wv * 16 + lc;  // 0..127
  const int cu = uh * 128 + unit_local; // 0..255
  const int erow = tid >> 5, ec8 = tid & 31;  // export mapping
  const int eba = (erow * 256 + ec8 * 8) ^ ((erow & 7) << 4);

  f32x4 cst = (f32x4){0.f, 0.f, 0.f, 0.f};
  f32x4 ownp[4];  // own-half K partial for step t (from h_{t-1} own half)
#pragma unroll
  for (int g = 0; g < 4; g++) ownp[g] = (f32x4){0.f, 0.f, 0.f, 0.f};

  for (int t = 0; t < 96; ++t) {
    const int tt = d ? 95 - t : t;
    const int par = (t - 1) & 1, par2 = t & 1;
    const int r16 = tt * 16 + bb;
    // xg loads issue first (hidden under the poll below)
    half4 xv[4];
#pragma unroll
    for (int g = 0; g < 4; g++)
      xv[g] = *(const half4*)&xg[(((size_t)d * 1536 + r16) * 64 +
                                  (g * 16 + uh * 8 + wv)) * 256 + ln * 4];
    f32x4 acc[4];
#pragma unroll
    for (int g = 0; g < 4; g++) {
#pragma unroll
      for (int r = 0; r < 4; r++) acc[g][r] = ownp[g][r] + (float)xv[g][r];
    }
    if (t > 0) {
      // wait for partner step t-1 (tripwire: deadlock -> wrong answer)
      unsigned spin = 0;
      while (__hip_atomic_load(pflag, __ATOMIC_RELAXED,
                               __HIP_MEMORY_SCOPE_AGENT) < base + t) {
        if (++spin > 65536u) break;
      }
      asm volatile("" ::: "memory");
      unsigned long long q[4][2];
#pragma unroll
      for (int j = 0; j < 4; j++) {
        const f16* p = &hpart[par * 2048 + lc * 128 + j * 32 + lk * 8];
        q[j][0] = __hip_atomic_load((const unsigned long long*)p,
                                    __ATOMIC_RELAXED, __HIP_MEMORY_SCOPE_AGENT);
        q[j][1] = __hip_atomic_load((const unsigned long long*)(p + 4),
                                    __ATOMIC_RELAXED, __HIP_MEMORY_SCOPE_AGENT);
      }
#pragma unroll
      for (int j = 0; j < 4; j++) {
        union { unsigned long long uq[2]; half8 h; } u;
        u.uq[0] = q[j][0]; u.uq[1] = q[j][1];
#pragma unroll
        for (int g = 0; g < 4; g++)
          acc[g] = mfma16(u.h, wfr[g * 8 + 4 + j], acc[g]);
      }
    }
    // LSTM cell, fully in registers (lane owns 4 rows x 1 unit)
    f16 hv[4];
#pragma unroll
    for (int r = 0; r < 4; r++) {
      float gi = sigf(acc[0][r]);
      float gf = sigf(acc[1][r]);
      float gg = tanhf2(acc[2][r]);
      float go = sigf(acc[3][r]);
      float cn = gf * cst[r] + gi * gg;
      cst[r] = cn;
      hv[r] = (f16)(go * tanhf2(cn));
    }
    // write own h into swizzled LDS tile
#pragma unroll
    for (int r = 0; r < 4; r++) {
      int row = lk * 4 + r;
      int ba = (row * 256 + unit_local * 2) ^ ((row & 7) << 4);
      *(f16*)&hl[par2][ba] = hv[r];
    }
    __syncthreads();  // B1: tile complete
    // publish: coalesced u64 export to hown, drain, release flag
    unsigned long long v = *(const unsigned long long*)&hl[par2][eba];
    __hip_atomic_store((unsigned long long*)&hown[par2 * 2048 + erow * 128 + ec8 * 4],
                       v, __ATOMIC_RELAXED, __HIP_MEMORY_SCOPE_AGENT);
    asm volatile("s_waitcnt vmcnt(0)" ::: "memory");
    __syncthreads();  // B2: all h stores drained
    if (tid == 0)
      __hip_atomic_store(myflag, base + t + 1, __ATOMIC_RELAXED,
                         __HIP_MEMORY_SCOPE_AGENT);
    // off critical path: sequence output (+ final states)
    *(unsigned long long*)&seqo[(size_t)tt * 131072 +
        (size_t)(rowbase + erow) * 512 + d * 256 + uh * 128 + ec8 * 4] = v;
    if (t == 95) {
      *(unsigned long long*)&hfin[(size_t)(rowbase + erow) * 512 +
                                  d * 256 + uh * 128 + ec8 * 4] = v;
#pragma unroll
      for (int r = 0; r < 4; r++)
        cfin[(size_t)(rowbase + lk * 4 + r) * 512 + d * 256 + cu] = cst[r];
    } else {
      // own-half K MFMAs for step t+1 (hides partner flag/L3 latency)
      half8 ao[4];
#pragma unroll
      for (int j = 0; j < 4; j++) {
        int ba = (lc * 256 + j * 64 + lk * 16) ^ ((lc & 7) << 4);
        ao[j] = *(const half8*)&hl[par2][ba];
      }
#pragma unroll
      for (int g = 0; g < 4; g++) {
        f32x4 s = (f32x4){0.f, 0.f, 0.f, 0.f};
#pragma unroll
        for (int j = 0; j < 4; j++) s = mfma16(ao[j], wfr[g * 8 + j], s);
        ownp[g] = s;
      }
    }
  }
}

// --------- decoder: one layer-eval; WG = 4 row-blocks x 32 units ----------
// grid (4,16): x=row64-block, y=unit-block(32 of 512). block 128 (2 waves).
// K-outer / row-inner with hoisted weight frags: W panel read 4x (was 16x).
__global__ __launch_bounds__(128) void dec_step(
    const f16* __restrict__ A0, int K0, const f16* __restrict__ A1,
    const f16* __restrict__ W, int Kt,
    const float* __restrict__ bih, const float* __restrict__ bhh,
    float* __restrict__ cst, f16* __restrict__ h1)
{
  const int u0 = blockIdx.y * 32;
  const int rb = blockIdx.x * 64;
  const int wv = threadIdx.x >> 6, ln = threadIdx.x & 63;
  const int lc = ln & 15, lk = ln >> 4;
  const int cu = u0 + wv * 16 + lc;  // unit 0..511
  f32x4 acc[4][4];  // [rr][g]
#pragma unroll
  for (int g = 0; g < 4; g++) {
    float b = bih[g * 512 + cu] + bhh[g * 512 + cu];
#pragma unroll
    for (int rr = 0; rr < 4; rr++) acc[rr][g] = (f32x4){b, b, b, b};
  }
  const int K0c = K0 >> 5, Ktc = Kt >> 5;
  for (int kc = 0; kc < Ktc; kc++) {
    const f16* Ap; int ko;
    if (kc < K0c) { Ap = A0; ko = kc * 32; }
    else          { Ap = A1; ko = (kc - K0c) * 32; }
    half8 b[4];
#pragma unroll
    for (int g = 0; g < 4; g++)
      b[g] = LD8(&W[(size_t)(g * 512 + cu) * Kt + kc * 32 + lk * 8]);
#pragma unroll
    for (int rr = 0; rr < 4; rr++) {
      half8 a = LD8(&Ap[(size_t)(rb + rr * 16 + lc) * 512 + ko + lk * 8]);
#pragma unroll
      for (int g = 0; g < 4; g++) acc[rr][g] = mfma16(a, b[g], acc[rr][g]);
    }
  }
#pragma unroll
  for (int rr = 0; rr < 4; rr++) {
#pragma unroll
    for (int r = 0; r < 4; r++) {
      const int row = rb + rr * 16 + lk * 4 + r;
      float gi = sigf(acc[rr][0][r]);
      float gf = sigf(acc[rr][1][r]);
      float gg = tanhf2(acc[rr][2][r]);
      float go = sigf(acc[rr][3][r]);
      float cp = cst[(size_t)row * 512 + cu];
      float cn = gf * cp + gi * gg;
      cst[(size_t)row * 512 + cu] = cn;
      h1[(size_t)row * 512 + cu] = (f16)(go * tanhf2(cn));
    }
  }
}

// --------- FC: out = h4 @ fcW^T + b; writes d_out slice + feedback --------
__global__ __launch_bounds__(64) void fc_kernel(
    const f16* __restrict__ hin, const f16* __restrict__ Wf,
    const float* __restrict__ bf, float* __restrict__ out,
    f16* __restrict__ zfc, int s)
{
  const int rb = blockIdx.x * 16;
  const int ln = threadIdx.x;
  f32x4 acc[4];
#pragma unroll
  for (int n = 0; n < 4; n++) acc[n] = (f32x4){0.f, 0.f, 0.f, 0.f};
#pragma unroll
  for (int kc = 0; kc < 16; kc++) {
    half8 a = LD8(&hin[(size_t)(rb + (ln & 15)) * 512 + kc * 32 + (ln >> 4) * 8]);
#pragma unroll
    for (int n = 0; n < 4; n++) {
      half8 b = LD8(&Wf[(size_t)(n * 16 + (ln & 15)) * 512 + kc * 32 + (ln >> 4) * 8]);
      acc[n] = mfma16(a, b, acc[n]);
    }
  }
#pragma unroll
  for (int n = 0; n < 4; n++) {
    const int col = n * 16 + (ln & 15);
    const float bb = bf[col];
#pragma unroll
    for (int r = 0; r < 4; r++) {
      const int row = rb + (ln >> 4) * 4 + r;
      float v = acc[n][r] + bb;
      out[(size_t)row * 896 + s * 64 + col] = v;
      zfc[(size_t)row * 512 + col] = (f16)v;
    }
  }
}

extern "C" void kernel_launch(void* const* d_in, const int* in_sizes, int n_in,
                              void* d_out, int out_size, void* d_ws, size_t ws_size,
                              hipStream_t stream) {
  char* ws = (char*)d_ws;
  const float* x     = (const float*)d_in[0];
  const float* eWih0 = (const float*)d_in[1];
  const float* eWhh0 = (const float*)d_in[2];
  const float* ebih0 = (const float*)d_in[3];
  const float* ebhh0 = (const float*)d_in[4];
  const float* eWih  = (const float*)d_in[5];
  const float* eWhh  = (const float*)d_in[6];
  const float* ebih  = (const float*)d_in[7];
  const float* ebhh  = (const float*)d_in[8];
  const float* dWih0 = (const float*)d_in[9];
  const float* dWhh0 = (const float*)d_in[10];
  const float* dbih0 = (const float*)d_in[11];
  const float* dbhh0 = (const float*)d_in[12];
  const float* dWih  = (const float*)d_in[13];
  const float* dWhh  = (const float*)d_in[14];
  const float* dbih  = (const float*)d_in[15];
  const float* dbhh  = (const float*)d_in[16];
  const float* fcW   = (const float*)d_in[17];
  const float* fcb   = (const float*)d_in[18];

  f16* xg    = (f16*)(ws + OFF_XG);
  f16* hbuf  = (f16*)(ws + OFF_HBUF);
  int* flags = (int*)(ws + OFF_FLAGS);
  f16* dhdb  = (f16*)(ws + OFF_DHDB);
  float* dcst = (float*)(ws + OFF_DCST);
  f16* zfc   = (f16*)(ws + OFF_ZFC);
  f16* seqA  = (f16*)(ws + OFF_SEQA);
  f16* seqB  = (f16*)(ws + OFF_SEQB);

  prep<<<dim3(2048), dim3(256), 0, stream>>>(x, eWih0, eWhh0, eWih, eWhh,
                                             dWih0, dWhh0, dWih, dWhh, fcW, ws);

  // ---------------- encoder ----------------
  for (int l = 0; l < 5; ++l) {
    const f16* Ain = (l == 0) ? (f16*)(ws + OFF_X16) : ((l & 1) ? seqA : seqB);
    const int K = (l == 0) ? 64 : 512;
    const f16* Wih = (l == 0) ? (f16*)(ws + OFF_WIH0)
                              : (f16*)(ws + OFF_WIH14) + (size_t)(l - 1) * 2 * 1024 * 512;
    const float* bi = (l == 0) ? ebih0 : ebih + (size_t)(l - 1) * 2048;
    const float* bh = (l == 0) ? ebhh0 : ebhh + (size_t)(l - 1) * 2048;
    gemm_xg<<<dim3(192, 16), dim3(256), 0, stream>>>(Ain, K, Wih, bi, bh, xg);

    const f16* whhf_l = (f16*)(ws + OFF_WHH) + (size_t)l * 524288;
    f16* so = (l & 1) ? seqB : seqA;
    enc_layer<<<dim3(16, 4), dim3(512), 0, stream>>>(
        xg, whhf_l, hbuf, flags, so,
        dhdb + (size_t)l * 131072, dcst + (size_t)l * 131072, l);
  }

  // ---------------- decoder ----------------
  for (int s = 0; s < 14; ++s) {
    const int p = s & 1;
    for (int l = 0; l < 5; ++l) {
      dec_step<<<dim3(4, 16), dim3(128), 0, stream>>>(
          (l == 0) ? zfc : dhdb + (size_t)(p ^ 1) * 655360 + (size_t)(l - 1) * 131072,
          (l == 0) ? 64 : 512,
          dhdb + (size_t)p * 655360 + (size_t)l * 131072,
          (l == 0) ? (f16*)(ws + OFF_WDEC0)
                   : (f16*)(ws + OFF_WDEC14) + (size_t)(l - 1) * 2048 * 1024,
          (l == 0) ? 576 : 1024,
          (l == 0) ? dbih0 : dbih + (size_t)(l - 1) * 2048,
          (l == 0) ? dbhh0 : dbhh + (size_t)(l - 1) * 2048,
          dcst + (size_t)l * 131072,
          dhdb + (size_t)(p ^ 1) * 655360 + (size_t)l * 131072);
    }
    fc_kernel<<<dim3(16), dim3(64), 0, stream>>>(
        dhdb + (size_t)(p ^ 1) * 655360 + 4 * 131072, (f16*)(ws + OFF_WFC), fcb,
        (float*)d_out, zfc, s);
  }
}

// Round 6
// 3862.687 us; speedup vs baseline: 1.6137x; 1.1077x over previous
//
// Seq2Seq BiLSTM (B=256,T=96,D=64,H=256,L=5, dec H2=512, P=14) — round 6.
// vs r5: enc_layer weights LDS-RESIDENT (compiler refused VGPR residency 3x:
// r2=64, r4=108, r5=104 VGPRs < 128 needed; spilled/re-streamed 256KB/step
// through L2 = the 2us/step floor). New: 8-way unit split, 256 WGs x 128 thr,
// 64KB Whh staged once into LDS; h exchange via relaxed agent u64 atomics
// (L3); tid0 8-flag poll + s_sleep; publish via padded LDS bounce -> coalesced
// u64 store -> vmcnt(0) -> bar -> flag; seqo/hfin/cfin after flag (off path).
// dec_step/gemm_xg/fc unchanged from r5.
#include <hip/hip_runtime.h>

typedef _Float16 f16;
using half8 = __attribute__((ext_vector_type(8))) _Float16;
using half4 = __attribute__((ext_vector_type(4))) _Float16;
using f32x4 = __attribute__((ext_vector_type(4))) float;

#define DEV __device__ __forceinline__
#define LD8(p) (*(const half8*)(const void*)(p))

DEV f32x4 mfma16(half8 a, half8 b, f32x4 c) {
  return __builtin_amdgcn_mfma_f32_16x16x32_f16(a, b, c, 0, 0, 0);
}
DEV float sigf(float x) { return 1.f / (1.f + __expf(-x)); }
DEV float tanhf2(float x) { float e = __expf(2.f * x); return 1.f - 2.f / (e + 1.f); }

// ---- workspace layout (byte offsets, all 256-aligned; total ~194 MB) ----
static const size_t OFF_WIH0   = 0;          // [2][1024][64] f16
static const size_t OFF_WIH14  = 262144;     // [4][2][1024][512] f16
static const size_t OFF_WHH    = 8650752;    // frag-major [5][d][uo8][tile2][g4][kc8][ln64][e8] f16
static const size_t OFF_WDEC0  = 13893632;   // [2048][576] f16 ([Wih|Whh])
static const size_t OFF_WDEC14 = 16252928;   // [4][2048][1024] f16
static const size_t OFF_WFC    = 33030144;   // [64][512] f16
static const size_t OFF_X16    = 33095680;   // [96][256][64] f16
static const size_t OFF_SEQA   = 36241408;   // [96][256][512] f16
static const size_t OFF_SEQB   = 61407232;   // [96][256][512] f16
static const size_t OFF_XG     = 86573056;   // frag-major [2][1536][64][64][4] f16
static const size_t OFF_HBUF   = 187236352;  // [16bb][2d][8uo][2par][16][32] f16 (512 KB)
static const size_t OFF_FLAGS  = 187760640;  // 256 ints
static const size_t OFF_DHDB   = 188284928;  // [2][5][256][512] f16 (parity,layer)
static const size_t OFF_DCST   = 190906368;  // [5][256][512] f32
static const size_t OFF_ZFC    = 193527808;  // [256][512] f16 (cols 0..63 used)

// ---------------- prep: convert/pack weights + x to f16 -------------------
__global__ __launch_bounds__(256) void prep(
    const float* __restrict__ x,
    const float* __restrict__ eWih0, const float* __restrict__ eWhh0,
    const float* __restrict__ eWih,  const float* __restrict__ eWhh,
    const float* __restrict__ dWih0, const float* __restrict__ dWhh0,
    const float* __restrict__ dWih,  const float* __restrict__ dWhh,
    const float* __restrict__ fcW,   char* __restrict__ ws)
{
  f16* wih0   = (f16*)(ws + OFF_WIH0);
  f16* wih14  = (f16*)(ws + OFF_WIH14);
  f16* whhf   = (f16*)(ws + OFF_WHH);
  f16* wdec0  = (f16*)(ws + OFF_WDEC0);
  f16* wdec14 = (f16*)(ws + OFF_WDEC14);
  f16* wfc    = (f16*)(ws + OFF_WFC);
  f16* x16    = (f16*)(ws + OFF_X16);
  f16* zfc    = (f16*)(ws + OFF_ZFC);
  int* flags  = (int*)(ws + OFF_FLAGS);
  const size_t total = 18137344;
  for (size_t i = (size_t)blockIdx.x * blockDim.x + threadIdx.x; i < total;
       i += (size_t)gridDim.x * blockDim.x) {
    size_t j = i;
    if (j < 131072) { wih0[j] = (f16)eWih0[j]; continue; }
    j -= 131072;
    if (j < 4194304) { wih14[j] = (f16)eWih[j]; continue; }
    j -= 4194304;
    if (j < 2621440) {  // Whh -> frag-major 8-way-split layout (dest linear=j)
      size_t l = j >> 19, i2 = j & 524287;
      int d   = (int)(i2 >> 18);
      int uo  = (int)((i2 >> 15) & 7);
      int tile= (int)((i2 >> 14) & 1);
      int g   = (int)((i2 >> 12) & 3);
      int kc  = (int)((i2 >> 9) & 7);
      int lnv = (int)((i2 >> 3) & 63);
      int e   = (int)(i2 & 7);
      int unit = uo * 32 + tile * 16 + (lnv & 15);
      int k = kc * 32 + (lnv >> 4) * 8 + e;
      int row = g * 256 + unit;
      float v = (l == 0) ? eWhh0[((size_t)d * 1024 + row) * 256 + k]
                         : eWhh[((((l - 1) * 2 + (size_t)d) * 1024) + row) * 256 + k];
      whhf[j] = (f16)v;
      continue;
    }
    j -= 2621440;
    if (j < 1179648) {  // dec layer0: [2048][64|512] -> [2048][576]
      size_t r = j / 576, c = j % 576;
      wdec0[j] = (f16)((c < 64) ? dWih0[r * 64 + c] : dWhh0[r * 512 + (c - 64)]);
      continue;
    }
    j -= 1179648;
    if (j < 8388608) {  // dec layers1-4: [2048][512|512] -> [2048][1024]
      size_t l = j >> 21, rem = j & 2097151;
      size_t r = rem >> 10, c = rem & 1023;
      wdec14[j] = (f16)((c < 512) ? dWih[(l * 2048 + r) * 512 + c]
                                  : dWhh[(l * 2048 + r) * 512 + (c - 512)]);
      continue;
    }
    j -= 8388608;
    if (j < 32768) { wfc[j] = (f16)fcW[j]; continue; }
    j -= 32768;
    if (j < 1572864) {  // x (B,T,D) -> x16 [t][b][d]
      size_t t = j >> 14, rem = j & 16383;
      size_t b = rem >> 6, d = rem & 63;
      x16[j] = (f16)x[(b * 96 + t) * 64 + d];
      continue;
    }
    j -= 1572864;
    if (j < 16384) {  // decoder first input = x[:, -1, :]
      size_t b = j >> 6, d = j & 63;
      zfc[b * 512 + d] = (f16)x[(b * 96 + 95) * 64 + d];
      continue;
    }
    j -= 16384;
    flags[j] = 0;  // 256 sync flags (ws is poisoned 0xAA each call)
  }
}

// ------------- phase A: Xg[dir][t,b][4H] = in @ Wih^T + (bih+bhh) ---------
__global__ __launch_bounds__(256) void gemm_xg(
    const f16* __restrict__ A, int K, const f16* __restrict__ W,
    const float* __restrict__ bih, const float* __restrict__ bhh,
    f16* __restrict__ xg)
{
  __shared__ __align__(16) f16 As[128 * 32];
  __shared__ __align__(16) f16 Ws[128 * 32];
  const int dir = blockIdx.y >> 3;
  const int cb  = (blockIdx.y & 7) * 128;
  const int rb  = blockIdx.x * 128;
  const int tid = threadIdx.x;
  const int wv = tid >> 6, ln = tid & 63;
  const int wr = wv >> 1, wc = wv & 1;
  const f16* Wd = W + (size_t)dir * 1024 * K;

  f32x4 acc[4][4];
#pragma unroll
  for (int m = 0; m < 4; m++)
#pragma unroll
    for (int n = 0; n < 4; n++) acc[m][n] = (f32x4){0.f, 0.f, 0.f, 0.f};

  const int sr = tid >> 1;
  const int sk = (tid & 1) * 16;
  const int nk = K >> 5;
  for (int kt = 0; kt < nk; ++kt) {
    half8 va0 = LD8(&A[(size_t)(rb + sr) * K + kt * 32 + sk]);
    half8 va1 = LD8(&A[(size_t)(rb + sr) * K + kt * 32 + sk + 8]);
    half8 vw0 = LD8(&Wd[(size_t)(cb + sr) * K + kt * 32 + sk]);
    half8 vw1 = LD8(&Wd[(size_t)(cb + sr) * K + kt * 32 + sk + 8]);
    *(half8*)&As[sr * 32 + sk] = va0;
    *(half8*)&As[sr * 32 + sk + 8] = va1;
    *(half8*)&Ws[sr * 32 + sk] = vw0;
    *(half8*)&Ws[sr * 32 + sk + 8] = vw1;
    __syncthreads();
    half8 af[4], bf[4];
#pragma unroll
    for (int m = 0; m < 4; m++)
      af[m] = LD8(&As[(wr * 64 + m * 16 + (ln & 15)) * 32 + (ln >> 4) * 8]);
#pragma unroll
    for (int n = 0; n < 4; n++)
      bf[n] = LD8(&Ws[(wc * 64 + n * 16 + (ln & 15)) * 32 + (ln >> 4) * 8]);
#pragma unroll
    for (int m = 0; m < 4; m++)
#pragma unroll
      for (int n = 0; n < 4; n++) acc[m][n] = mfma16(af[m], bf[n], acc[m][n]);
    __syncthreads();
  }
#pragma unroll
  for (int n = 0; n < 4; n++) {
    const int col = cb + wc * 64 + n * 16 + (ln & 15);
    const float bsum = bih[dir * 1024 + col] + bhh[dir * 1024 + col];
    const int c16 = (cb + wc * 64 + n * 16) >> 4;
#pragma unroll
    for (int m = 0; m < 4; m++) {
      const int r16 = (rb + wr * 64 + m * 16) >> 4;
      half4 h;
#pragma unroll
      for (int r = 0; r < 4; r++) h[r] = (f16)(acc[m][n][r] + bsum);
      *(half4*)&xg[(((size_t)dir * 1536 + r16) * 64 + c16) * 256 + ln * 4] = h;
    }
  }
}

// --------- persistent encoder layer v4: LDS-resident weights --------------
// grid (16,16): x=bb, y=d*8+uo. 128 thr / 2 waves. WG owns 32 units (octant
// uo), all 4 gates, K=256. Whh slice (64 KB) staged ONCE into LDS; per-step
// B-frags are conflict-free ds_read_b128. h_{t-1} read as 8 slices via
// relaxed agent u64 atomics (L3-coherent); own h published via padded LDS
// bounce -> coalesced u64 agent store -> vmcnt(0) -> bar -> flag.
__global__ __launch_bounds__(128) void enc_layer(
    const f16* __restrict__ xg, const f16* __restrict__ whhf,
    f16* __restrict__ hbuf, int* __restrict__ flags,
    f16* __restrict__ seqo, f16* __restrict__ hfin, float* __restrict__ cfin,
    int layer)
{
  const int bb = blockIdx.x;
  const int d = blockIdx.y >> 3, uo = blockIdx.y & 7;
  const int tid = threadIdx.x;
  const int wv = tid >> 6, ln = tid & 63;
  const int lc = ln & 15, lk = ln >> 4;

  __shared__ __align__(16) f16 wL[32768];   // [tile2][g4][kc8][ln64][e8] 64 KB
  __shared__ __align__(16) f16 hB[16 * 36]; // bounce, row stride 36 (bank-spread)

  // one-time weight stage: 64 KB global -> LDS, coalesced half8 copies
  const f16* wsrc = whhf + (size_t)(d * 8 + uo) * 32768;
#pragma unroll 4
  for (int i = 0; i < 32; i++)
    *(half8*)&wL[(i * 128 + tid) * 8] = LD8(&wsrc[(size_t)(i * 128 + tid) * 8]);
  __syncthreads();

  int* gflags = &flags[(bb * 2 + d) * 8];
  int* myflag = &gflags[uo];
  const f16* hgrp = hbuf + (size_t)(bb * 2 + d) * 8192;       // 8 slices x 2 par x 512
  f16* hown = hbuf + (size_t)((bb * 2 + d) * 8 + uo) * 1024;  // 2 par x 512
  const int base = layer * 96;
  const int rowbase = bb * 16;
  const int cu = uo * 32 + wv * 16 + lc;      // global unit of lane
  const int erow = tid >> 3, eu8 = tid & 7;   // export mapping (u64/thread)

  f32x4 cst = (f32x4){0.f, 0.f, 0.f, 0.f};

  for (int t = 0; t < 96; ++t) {
    const int tt = d ? 95 - t : t;
    const int par = (t - 1) & 1, par2 = t & 1;
    const int r16 = tt * 16 + bb;
    // xg loads issue first (independent of sync)
    half4 xv[4];
#pragma unroll
    for (int g = 0; g < 4; g++)
      xv[g] = *(const half4*)&xg[(((size_t)d * 1536 + r16) * 64 +
                                  (g * 16 + uo * 2 + wv)) * 256 + ln * 4];
    unsigned long long q[8][2];
    if (t > 0) {
      if (tid == 0) {  // single-thread group poll (8 flags in one 32B line)
        unsigned spin = 0;
        for (;;) {
          int mn = 0x7fffffff;
#pragma unroll
          for (int p = 0; p < 8; p++) {
            int f = __hip_atomic_load(&gflags[p], __ATOMIC_RELAXED,
                                      __HIP_MEMORY_SCOPE_AGENT);
            mn = (f < mn) ? f : mn;
          }
          if (mn >= base + t || ++spin > 100000u) break;
          __builtin_amdgcn_s_sleep(1);
        }
      }
      __syncthreads();
      // h_{t-1}[16][256] as 8 slices of [16][32], coherent u64 loads
#pragma unroll
      for (int j = 0; j < 8; j++) {
        const f16* p = hgrp + (size_t)(j * 2 + par) * 512 + lc * 32 + lk * 8;
        q[j][0] = __hip_atomic_load((const unsigned long long*)p,
                                    __ATOMIC_RELAXED, __HIP_MEMORY_SCOPE_AGENT);
        q[j][1] = __hip_atomic_load((const unsigned long long*)(p + 4),
                                    __ATOMIC_RELAXED, __HIP_MEMORY_SCOPE_AGENT);
      }
    }
    f32x4 acc[4];
#pragma unroll
    for (int g = 0; g < 4; g++)
      acc[g] = (f32x4){(float)xv[g][0], (float)xv[g][1],
                       (float)xv[g][2], (float)xv[g][3]};
    if (t > 0) {
#pragma unroll
      for (int j = 0; j < 8; j++) {
        union { unsigned long long uq[2]; half8 h; } u;
        u.uq[0] = q[j][0]; u.uq[1] = q[j][1];
#pragma unroll
        for (int g = 0; g < 4; g++) {
          half8 b = *(const half8*)&wL[(size_t)(((wv * 4 + g) * 8 + j) * 64 + ln) * 8];
          acc[g] = mfma16(u.h, b, acc[g]);
        }
      }
    }
    // LSTM cell, fully in registers (lane owns 4 rows x 1 unit)
    f16 hv[4];
#pragma unroll
    for (int r = 0; r < 4; r++) {
      float gi = sigf(acc[0][r]);
      float gf = sigf(acc[1][r]);
      float gg = tanhf2(acc[2][r]);
      float go = sigf(acc[3][r]);
      float cn = gf * cst[r] + gi * gg;
      cst[r] = cn;
      hv[r] = (f16)(go * tanhf2(cn));
    }
    // bounce -> coalesced publish
#pragma unroll
    for (int r = 0; r < 4; r++)
      hB[(lk * 4 + r) * 36 + wv * 16 + lc] = hv[r];
    __syncthreads();  // B1: bounce complete
    unsigned long long v = *(const unsigned long long*)&hB[erow * 36 + eu8 * 4];
    __hip_atomic_store((unsigned long long*)&hown[par2 * 512 + erow * 32 + eu8 * 4],
                       v, __ATOMIC_RELAXED, __HIP_MEMORY_SCOPE_AGENT);
    asm volatile("s_waitcnt vmcnt(0)" ::: "memory");  // own-h store acked
    __syncthreads();  // B2: whole WG drained (also protects hB reuse)
    if (tid == 0)
      __hip_atomic_store(myflag, base + t + 1, __ATOMIC_RELAXED,
                         __HIP_MEMORY_SCOPE_AGENT);
    // off critical path: sequence output (+ final states)
    *(unsigned long long*)&seqo[(size_t)tt * 131072 +
        (size_t)(rowbase + erow) * 512 + d * 256 + uo * 32 + eu8 * 4] = v;
    if (t == 95) {
      *(unsigned long long*)&hfin[(size_t)(rowbase + erow) * 512 +
                                  d * 256 + uo * 32 + eu8 * 4] = v;
#pragma unroll
      for (int r = 0; r < 4; r++)
        cfin[(size_t)(rowbase + lk * 4 + r) * 512 + d * 256 + cu] = cst[r];
    }
  }
}

// --------- decoder: one layer-eval; WG = 4 row-blocks x 32 units ----------
__global__ __launch_bounds__(128) void dec_step(
    const f16* __restrict__ A0, int K0, const f16* __restrict__ A1,
    const f16* __restrict__ W, int Kt,
    const float* __restrict__ bih, const float* __restrict__ bhh,
    float* __restrict__ cst, f16* __restrict__ h1)
{
  const int u0 = blockIdx.y * 32;
  const int rb = blockIdx.x * 64;
  const int wv = threadIdx.x >> 6, ln = threadIdx.x & 63;
  const int lc = ln & 15, lk = ln >> 4;
  const int cu = u0 + wv * 16 + lc;  // unit 0..511
  f32x4 acc[4][4];  // [rr][g]
#pragma unroll
  for (int g = 0; g < 4; g++) {
    float b = bih[g * 512 + cu] + bhh[g * 512 + cu];
#pragma unroll
    for (int rr = 0; rr < 4; rr++) acc[rr][g] = (f32x4){b, b, b, b};
  }
  const int K0c = K0 >> 5, Ktc = Kt >> 5;
  for (int kc = 0; kc < Ktc; kc++) {
    const f16* Ap; int ko;
    if (kc < K0c) { Ap = A0; ko = kc * 32; }
    else          { Ap = A1; ko = (kc - K0c) * 32; }
    half8 b[4];
#pragma unroll
    for (int g = 0; g < 4; g++)
      b[g] = LD8(&W[(size_t)(g * 512 + cu) * Kt + kc * 32 + lk * 8]);
#pragma unroll
    for (int rr = 0; rr < 4; rr++) {
      half8 a = LD8(&Ap[(size_t)(rb + rr * 16 + lc) * 512 + ko + lk * 8]);
#pragma unroll
      for (int g = 0; g < 4; g++) acc[rr][g] = mfma16(a, b[g], acc[rr][g]);
    }
  }
#pragma unroll
  for (int rr = 0; rr < 4; rr++) {
#pragma unroll
    for (int r = 0; r < 4; r++) {
      const int row = rb + rr * 16 + lk * 4 + r;
      float gi = sigf(acc[rr][0][r]);
      float gf = sigf(acc[rr][1][r]);
      float gg = tanhf2(acc[rr][2][r]);
      float go = sigf(acc[rr][3][r]);
      float cp = cst[(size_t)row * 512 + cu];
      float cn = gf * cp + gi * gg;
      cst[(size_t)row * 512 + cu] = cn;
      h1[(size_t)row * 512 + cu] = (f16)(go * tanhf2(cn));
    }
  }
}

// --------- FC: out = h4 @ fcW^T + b; writes d_out slice + feedback --------
__global__ __launch_bounds__(64) void fc_kernel(
    const f16* __restrict__ hin, const f16* __restrict__ Wf,
    const float* __restrict__ bf, float* __restrict__ out,
    f16* __restrict__ zfc, int s)
{
  const int rb = blockIdx.x * 16;
  const int ln = threadIdx.x;
  f32x4 acc[4];
#pragma unroll
  for (int n = 0; n < 4; n++) acc[n] = (f32x4){0.f, 0.f, 0.f, 0.f};
#pragma unroll
  for (int kc = 0; kc < 16; kc++) {
    half8 a = LD8(&hin[(size_t)(rb + (ln & 15)) * 512 + kc * 32 + (ln >> 4) * 8]);
#pragma unroll
    for (int n = 0; n < 4; n++) {
      half8 b = LD8(&Wf[(size_t)(n * 16 + (ln & 15)) * 512 + kc * 32 + (ln >> 4) * 8]);
      acc[n] = mfma16(a, b, acc[n]);
    }
  }
#pragma unroll
  for (int n = 0; n < 4; n++) {
    const int col = n * 16 + (ln & 15);
    const float bb = bf[col];
#pragma unroll
    for (int r = 0; r < 4; r++) {
      const int row = rb + (ln >> 4) * 4 + r;
      float v = acc[n][r] + bb;
      out[(size_t)row * 896 + s * 64 + col] = v;
      zfc[(size_t)row * 512 + col] = (f16)v;
    }
  }
}

extern "C" void kernel_launch(void* const* d_in, const int* in_sizes, int n_in,
                              void* d_out, int out_size, void* d_ws, size_t ws_size,
                              hipStream_t stream) {
  char* ws = (char*)d_ws;
  const float* x     = (const float*)d_in[0];
  const float* eWih0 = (const float*)d_in[1];
  const float* eWhh0 = (const float*)d_in[2];
  const float* ebih0 = (const float*)d_in[3];
  const float* ebhh0 = (const float*)d_in[4];
  const float* eWih  = (const float*)d_in[5];
  const float* eWhh  = (const float*)d_in[6];
  const float* ebih  = (const float*)d_in[7];
  const float* ebhh  = (const float*)d_in[8];
  const float* dWih0 = (const float*)d_in[9];
  const float* dWhh0 = (const float*)d_in[10];
  const float* dbih0 = (const float*)d_in[11];
  const float* dbhh0 = (const float*)d_in[12];
  const float* dWih  = (const float*)d_in[13];
  const float* dWhh  = (const float*)d_in[14];
  const float* dbih  = (const float*)d_in[15];
  const float* dbhh  = (const float*)d_in[16];
  const float* fcW   = (const float*)d_in[17];
  const float* fcb   = (const float*)d_in[18];

  f16* xg    = (f16*)(ws + OFF_XG);
  f16* hbuf  = (f16*)(ws + OFF_HBUF);
  int* flags = (int*)(ws + OFF_FLAGS);
  f16* dhdb  = (f16*)(ws + OFF_DHDB);
  float* dcst = (float*)(ws + OFF_DCST);
  f16* zfc   = (f16*)(ws + OFF_ZFC);
  f16* seqA  = (f16*)(ws + OFF_SEQA);
  f16* seqB  = (f16*)(ws + OFF_SEQB);

  prep<<<dim3(2048), dim3(256), 0, stream>>>(x, eWih0, eWhh0, eWih, eWhh,
                                             dWih0, dWhh0, dWih, dWhh, fcW, ws);

  // ---------------- encoder ----------------
  for (int l = 0; l < 5; ++l) {
    const f16* Ain = (l == 0) ? (f16*)(ws + OFF_X16) : ((l & 1) ? seqA : seqB);
    const int K = (l == 0) ? 64 : 512;
    const f16* Wih = (l == 0) ? (f16*)(ws + OFF_WIH0)
                              : (f16*)(ws + OFF_WIH14) + (size_t)(l - 1) * 2 * 1024 * 512;
    const float* bi = (l == 0) ? ebih0 : ebih + (size_t)(l - 1) * 2048;
    const float* bh = (l == 0) ? ebhh0 : ebhh + (size_t)(l - 1) * 2048;
    gemm_xg<<<dim3(192, 16), dim3(256), 0, stream>>>(Ain, K, Wih, bi, bh, xg);

    const f16* whhf_l = (f16*)(ws + OFF_WHH) + (size_t)l * 524288;
    f16* so = (l & 1) ? seqB : seqA;
    enc_layer<<<dim3(16, 16), dim3(128), 0, stream>>>(
        xg, whhf_l, hbuf, flags, so,
        dhdb + (size_t)l * 131072, dcst + (size_t)l * 131072, l);
  }

  // ---------------- decoder ----------------
  for (int s = 0; s < 14; ++s) {
    const int p = s & 1;
    for (int l = 0; l < 5; ++l) {
      dec_step<<<dim3(4, 16), dim3(128), 0, stream>>>(
          (l == 0) ? zfc : dhdb + (size_t)(p ^ 1) * 655360 + (size_t)(l - 1) * 131072,
          (l == 0) ? 64 : 512,
          dhdb + (size_t)p * 655360 + (size_t)l * 131072,
          (l == 0) ? (f16*)(ws + OFF_WDEC0)
                   : (f16*)(ws + OFF_WDEC14) + (size_t)(l - 1) * 2048 * 1024,
          (l == 0) ? 576 : 1024,
          (l == 0) ? dbih0 : dbih + (size_t)(l - 1) * 2048,
          (l == 0) ? dbhh0 : dbhh + (size_t)(l - 1) * 2048,
          dcst + (size_t)l * 131072,
          dhdb + (size_t)(p ^ 1) * 655360 + (size_t)l * 131072);
    }
    fc_kernel<<<dim3(16), dim3(64), 0, stream>>>(
        dhdb + (size_t)(p ^ 1) * 655360 + 4 * 131072, (f16*)(ws + OFF_WFC), fcb,
        (float*)d_out, zfc, s);
  }
}